// Round 1
// baseline (20598.703 us; speedup 1.0000x reference)
//
#include <hip/hip_runtime.h>
#include <math.h>

// Model dims (fixed by the reference)
#define D_     1024
#define H_     8
#define HD_    128
#define NR_    4
#define B_     2
#define SQ_    1024
#define SKV_   512
#define SKVT_  2048
#define VOCAB_ 32000
#define NL_    6
#define FF_    4096
#define EPS_   1e-6f

// ---------------------------------------------------------------------------
// Generic tiled fp32 GEMM:  C[z][m][n] = scale * sum_k A[z][m][k]*B[z][(n,k)] + bias[n]
//   A: row-major [M,K], row stride lda, per-z offset sA
//   B: if !BTRANS: row-major [N,K] (weight layout, C = A @ B^T), row stride ldb
//      if  BTRANS: row-major [K,N] (C = A @ B), row stride ldb
//   C: row stride ldc, per-z offset sC
// 128x128 tile, BK=16, 256 threads, 8x8 per thread. K must be a multiple of 16.
// ---------------------------------------------------------------------------
template<bool BTRANS>
__global__ __launch_bounds__(256)
void k_gemm(const float* __restrict__ A, int lda, long long sA,
            const float* __restrict__ B, int ldb, long long sB,
            float* __restrict__ C, int ldc, long long sC,
            int M, int N, int K, float scale, const float* __restrict__ bias)
{
    __shared__ float As[16][128];
    __shared__ float Bs[16][128];

    const int z = blockIdx.z;
    A += (long long)z * sA;
    B += (long long)z * sB;
    C += (long long)z * sC;

    const int m0 = blockIdx.y * 128;
    const int n0 = blockIdx.x * 128;
    const int tid = threadIdx.x;
    const int tm = tid >> 4;         // 0..15
    const int tn = tid & 15;         // 0..15
    const int lr = tid >> 2;         // 0..63
    const int lc = (tid & 3) << 2;   // 0,4,8,12

    float acc[8][8];
#pragma unroll
    for (int i = 0; i < 8; ++i)
#pragma unroll
        for (int j = 0; j < 8; ++j) acc[i][j] = 0.f;

    for (int k0 = 0; k0 < K; k0 += 16) {
        // --- stage A tile (transposed into As[k][m]) ---
#pragma unroll
        for (int r = 0; r < 2; ++r) {
            int m = lr + r * 64;
            float4 av = make_float4(0.f, 0.f, 0.f, 0.f);
            if (m0 + m < M)
                av = *(const float4*)(A + (long long)(m0 + m) * lda + (k0 + lc));
            As[lc + 0][m] = av.x; As[lc + 1][m] = av.y;
            As[lc + 2][m] = av.z; As[lc + 3][m] = av.w;
        }
        // --- stage B tile into Bs[k][n] ---
        if (!BTRANS) {
#pragma unroll
            for (int r = 0; r < 2; ++r) {
                int n = lr + r * 64;
                float4 bv = make_float4(0.f, 0.f, 0.f, 0.f);
                if (n0 + n < N)
                    bv = *(const float4*)(B + (long long)(n0 + n) * ldb + (k0 + lc));
                Bs[lc + 0][n] = bv.x; Bs[lc + 1][n] = bv.y;
                Bs[lc + 2][n] = bv.z; Bs[lc + 3][n] = bv.w;
            }
        } else {
            int kk = tid >> 5;           // 0..7
            int nn = (tid & 31) << 2;    // 0..124
#pragma unroll
            for (int r = 0; r < 2; ++r) {
                int k = kk + r * 8;
                float4 bv = make_float4(0.f, 0.f, 0.f, 0.f);
                if (n0 + nn < N)   // BTRANS callers have N % 4 == 0
                    bv = *(const float4*)(B + (long long)(k0 + k) * ldb + (n0 + nn));
                *(float4*)&Bs[k][nn] = bv;
            }
        }
        __syncthreads();

#pragma unroll
        for (int kk = 0; kk < 16; ++kk) {
            float a[8], b[8];
            *(float4*)&a[0] = *(const float4*)&As[kk][tm * 8];
            *(float4*)&a[4] = *(const float4*)&As[kk][tm * 8 + 4];
            *(float4*)&b[0] = *(const float4*)&Bs[kk][tn * 8];
            *(float4*)&b[4] = *(const float4*)&Bs[kk][tn * 8 + 4];
#pragma unroll
            for (int i = 0; i < 8; ++i)
#pragma unroll
                for (int j = 0; j < 8; ++j)
                    acc[i][j] = fmaf(a[i], b[j], acc[i][j]);
        }
        __syncthreads();
    }

#pragma unroll
    for (int i = 0; i < 8; ++i) {
        int m = m0 + tm * 8 + i;
        if (m < M) {
#pragma unroll
            for (int j = 0; j < 8; ++j) {
                int n = n0 + tn * 8 + j;
                if (n < N) {
                    float v = acc[i][j] * scale;
                    if (bias) v += bias[n];
                    C[(long long)m * ldc + n] = v;
                }
            }
        }
    }
}

// ---------------------------------------------------------------------------
// RMSNorm over rows of length 1024. One block (256 thr) per row.
// ---------------------------------------------------------------------------
__global__ __launch_bounds__(256)
void k_rmsnorm(const float* __restrict__ x, const float* __restrict__ w,
               float* __restrict__ y)
{
    long long row = blockIdx.x;
    const float* xr = x + row * D_;
    float* yr = y + row * D_;
    int tid = threadIdx.x;

    float4 v = *(const float4*)(xr + tid * 4);
    float ss = v.x * v.x + v.y * v.y + v.z * v.z + v.w * v.w;
#pragma unroll
    for (int off = 32; off >= 1; off >>= 1) ss += __shfl_xor(ss, off);
    __shared__ float red[4];
    if ((tid & 63) == 0) red[tid >> 6] = ss;
    __syncthreads();
    float tot = red[0] + red[1] + red[2] + red[3];
    float sc = 1.0f / sqrtf(tot * (1.0f / D_) + EPS_);

    float4 wv = *(const float4*)(w + tid * 4);
    float4 o;
    o.x = v.x * sc * wv.x; o.y = v.y * sc * wv.y;
    o.z = v.z * sc * wv.z; o.w = v.w * sc * wv.w;
    *(float4*)(yr + tid * 4) = o;
}

// ---------------------------------------------------------------------------
// Row softmax (in place). One block per row, N <= 2048.
// ---------------------------------------------------------------------------
__global__ __launch_bounds__(256)
void k_softmax(float* __restrict__ S, int N)
{
    __shared__ float buf[2048];
    __shared__ float red[4];
    long long row = blockIdx.x;
    float* p = S + row * (long long)N;
    int tid = threadIdx.x;

    float mx = -1e30f;
    for (int i = tid; i < N; i += 256) { float v = p[i]; buf[i] = v; mx = fmaxf(mx, v); }
#pragma unroll
    for (int off = 32; off >= 1; off >>= 1) mx = fmaxf(mx, __shfl_xor(mx, off));
    if ((tid & 63) == 0) red[tid >> 6] = mx;
    __syncthreads();
    mx = fmaxf(fmaxf(red[0], red[1]), fmaxf(red[2], red[3]));

    float sum = 0.f;
    for (int i = tid; i < N; i += 256) { float e = __expf(buf[i] - mx); buf[i] = e; sum += e; }
#pragma unroll
    for (int off = 32; off >= 1; off >>= 1) sum += __shfl_xor(sum, off);
    __syncthreads();
    if ((tid & 63) == 0) red[tid >> 6] = sum;
    __syncthreads();
    sum = red[0] + red[1] + red[2] + red[3];
    float inv = 1.0f / sum;
    for (int i = tid; i < N; i += 256) p[i] = buf[i] * inv;
}

// ---------------------------------------------------------------------------
// all_kv[b, n*SKV+s, d] = rh[n,b,s,d] * conf[b,n]
// ---------------------------------------------------------------------------
__global__ void k_weighted_kv(const float* __restrict__ rh,
                              const float* __restrict__ conf,
                              float* __restrict__ kv)
{
    int idx = blockIdx.x * 256 + threadIdx.x;      // B*NR*SKV*D = 2^22
    int d = idx & (D_ - 1);
    int s = (idx >> 10) & (SKV_ - 1);
    int n = (idx >> 19) & (NR_ - 1);
    int b = idx >> 21;
    float c = conf[b * NR_ + n];
    kv[idx] = rh[(((long long)(n * B_ + b) * SKV_ + s) * D_) + d] * c;
}

// summaries[b, n*D+d] = mean_s rh[n,b,s,d]
__global__ void k_summaries(const float* __restrict__ rh, float* __restrict__ sm)
{
    int idx = blockIdx.x * 256 + threadIdx.x;      // B*NR*D = 8192
    int d = idx & (D_ - 1);
    int n = (idx >> 10) & (NR_ - 1);
    int b = idx >> 12;
    const float* p = rh + ((long long)(n * B_ + b) * SKV_) * D_ + d;
    float s = 0.f;
    for (int t = 0; t < SKV_; ++t) s += p[(long long)t * D_];
    sm[idx] = s * (1.0f / SKV_);
}

// out[m,n] = mean_h S[h,m,n]   (per batch), N columns
__global__ void k_attn_mean(const float* __restrict__ S, float* __restrict__ O)
{
    int idx = blockIdx.x * 256 + threadIdx.x;      // SQ*SKVT = 2^21
    float s = 0.f;
#pragma unroll
    for (int h = 0; h < H_; ++h) s += S[(long long)h * SQ_ * SKVT_ + idx];
    O[idx] = s * (1.0f / H_);
}

// RoPE applied in place to q and k, layout [B,SQ,D], head-dim 128
__global__ void k_rope(float* __restrict__ q, float* __restrict__ k)
{
    int idx = blockIdx.x * 256 + threadIdx.x;      // B*SQ*H*64 = 2^20
    int j = idx & 63;
    int h = (idx >> 6) & (H_ - 1);
    int s = (idx >> 9) & (SQ_ - 1);
    int b = idx >> 19;
    float inv = __expf(-9.210340371976184f * (float)j * (1.0f / 64.0f)); // 10000^(-j/64)
    float ang = (float)s * inv;
    float sn, cs;
    __sincosf(ang, &sn, &cs);
    long long base = ((long long)(b * SQ_ + s)) * D_ + h * HD_ + j;
    float q1 = q[base], q2 = q[base + 64];
    q[base]      = q1 * cs - q2 * sn;
    q[base + 64] = q2 * cs + q1 * sn;
    float k1 = k[base], k2 = k[base + 64];
    k[base]      = k1 * cs - k2 * sn;
    k[base + 64] = k2 * cs + k1 * sn;
}

// y += a (float4)
__global__ void k_add(float* __restrict__ y, const float* __restrict__ a)
{
    int i = blockIdx.x * 256 + threadIdx.x;
    float4 v = *(const float4*)(y + i * 4);
    float4 u = *(const float4*)(a + i * 4);
    v.x += u.x; v.y += u.y; v.z += u.z; v.w += u.w;
    *(float4*)(y + i * 4) = v;
}

// x[b,s,:] += ag[b,:]
__global__ void k_add_bcast(float* __restrict__ x, const float* __restrict__ ag)
{
    int idx = blockIdx.x * 256 + threadIdx.x;   // B*SQ*D = 2^21
    int d = idx & (D_ - 1);
    int b = idx >> 20;
    x[idx] += ag[b * D_ + d];
}

// exact GELU in place
__global__ void k_gelu(float* __restrict__ v, int n)
{
    int i = blockIdx.x * 256 + threadIdx.x;
    if (i < n) {
        float x = v[i];
        v[i] = 0.5f * x * (1.0f + erff(x * 0.7071067811865476f));
    }
}

// g = silu(g) * u
__global__ void k_silu_mul(float* __restrict__ g, const float* __restrict__ u)
{
    int i = blockIdx.x * 256 + threadIdx.x;
    float x = g[i];
    g[i] = (x / (1.0f + __expf(-x))) * u[i];
}

// pooled[b,d] = mean_s h[b,s,d]
__global__ void k_meanpool(const float* __restrict__ h, float* __restrict__ p)
{
    int idx = blockIdx.x * 256 + threadIdx.x;   // B*D = 2048
    int d = idx & (D_ - 1);
    int b = idx >> 10;
    const float* r = h + ((long long)b * SQ_) * D_ + d;
    float s = 0.f;
    for (int t = 0; t < SQ_; ++t) s += r[(long long)t * D_];
    p[idx] = s * (1.0f / SQ_);
}

// ---------------------------------------------------------------------------
// host side
// ---------------------------------------------------------------------------
static void gemm(hipStream_t st,
                 const float* A, int lda, long long sA,
                 const float* B, int ldb, long long sB,
                 float* C, int ldc, long long sC,
                 int Z, int M, int N, int K, float scale, const float* bias,
                 bool btrans)
{
    dim3 g((N + 127) / 128, (M + 127) / 128, Z);
    if (btrans)
        k_gemm<true><<<g, 256, 0, st>>>(A, lda, sA, B, ldb, sB, C, ldc, sC, M, N, K, scale, bias);
    else
        k_gemm<false><<<g, 256, 0, st>>>(A, lda, sA, B, ldb, sB, C, ldc, sC, M, N, K, scale, bias);
}

extern "C" void kernel_launch(void* const* d_in, const int* in_sizes, int n_in,
                              void* d_out, int out_size, void* d_ws, size_t ws_size,
                              hipStream_t stream)
{
    const float* rh     = (const float*)d_in[0];
    const float* conf   = (const float*)d_in[1];
    // d_in[2] = rh_roles (unused)
    const float* qh     = (const float*)d_in[3];
    const float* cainw  = (const float*)d_in[4];
    const float* cainb  = (const float*)d_in[5];
    const float* caoutw = (const float*)d_in[6];
    const float* caoutb = (const float*)d_in[7];
    const float* cnorm  = (const float*)d_in[8];
    const float* agw1   = (const float*)d_in[9];
    const float* agb1   = (const float*)d_in[10];
    const float* agw2   = (const float*)d_in[11];
    const float* agb2   = (const float*)d_in[12];
    const float* agnw   = (const float*)d_in[13];
    const float* n1w    = (const float*)d_in[14];
    const float* wq     = (const float*)d_in[15];
    const float* wk     = (const float*)d_in[16];
    const float* wv     = (const float*)d_in[17];
    const float* wo     = (const float*)d_in[18];
    const float* n2w    = (const float*)d_in[19];
    const float* wg     = (const float*)d_in[20];
    const float* wu     = (const float*)d_in[21];
    const float* wdn    = (const float*)d_in[22];
    const float* gnw    = (const float*)d_in[23];
    const float* lmw    = (const float*)d_in[24];
    const float* mw1    = (const float*)d_in[25];
    const float* mb1    = (const float*)d_in[26];
    const float* mw2    = (const float*)d_in[27];
    const float* mb2    = (const float*)d_in[28];

    float* out    = (float*)d_out;
    float* logits = out;                 // [2,1024,32000] = 65,536,000
    float* meta   = out + 65536000;      // [2,3]
    float* attnw  = out + 65536006;      // [2,1024,2048]

    // workspace carve-up (floats)
    float* ws    = (float*)d_ws;
    float* allkv = ws;                   //  4,194,304  [B,2048,D]
    float* xb    = allkv + 4194304;      //  2,097,152  [B,SQ,D]
    float* hb    = xb + 2097152;
    float* qb    = hb + 2097152;
    float* ctx   = qb + 2097152;
    float* ob    = ctx + 2097152;
    float* kb    = ob + 2097152;         //  4,194,304
    float* vb    = kb + 4194304;         //  4,194,304
    float* sb    = vb + 4194304;         // 16,777,216 (scores; overlaps FFN bufs)
    float* ffg   = sb;
    float* ffu   = sb + 8388608;
    float* sml   = sb + 16777216;
    float* summ  = sml;                  // 8192
    float* agh   = summ + 8192;          // 4096
    float* ago   = agh + 4096;           // 2048
    float* agr   = ago + 2048;           // 2048
    float* pooled= agr + 2048;           // 2048
    float* mbuf  = pooled + 2048;        // 512
    if (ws_size < (size_t)39911424 * 4) return;  // need ~152 MiB

    const float iscale = 0.08838834764831845f;   // 1/sqrt(128)

    // --- stage 0 ---
    k_weighted_kv<<<16384, 256, 0, stream>>>(rh, conf, allkv);
    k_summaries<<<32, 256, 0, stream>>>(rh, summ);
    hipMemcpyAsync(xb, qh, (size_t)2097152 * 4, hipMemcpyDeviceToDevice, stream);

    // --- cross-attention x2 ---
    for (int i = 0; i < 2; ++i) {
        const float* inw = cainw + (size_t)i * 3 * D_ * D_;
        const float* inb = cainb + (size_t)i * 3 * D_;
        k_rmsnorm<<<B_ * SQ_, 256, 0, stream>>>(xb, cnorm + i * D_, hb);
        gemm(stream, hb, D_, 0, inw, D_, 0, qb, D_, 0, 1, B_ * SQ_, D_, D_, 1.f, inb, false);
        gemm(stream, allkv, D_, 0, inw + 1048576, D_, 0, kb, D_, 0, 1, B_ * SKVT_, D_, D_, 1.f, inb + D_, false);
        gemm(stream, allkv, D_, 0, inw + 2097152, D_, 0, vb, D_, 0, 1, B_ * SKVT_, D_, D_, 1.f, inb + 2 * D_, false);
        for (int b = 0; b < B_; ++b) {
            gemm(stream, qb + (size_t)b * SQ_ * D_, D_, HD_,
                 kb + (size_t)b * SKVT_ * D_, D_, HD_,
                 sb, SKVT_, (long long)SQ_ * SKVT_,
                 H_, SQ_, SKVT_, HD_, iscale, nullptr, false);
            k_softmax<<<H_ * SQ_, 256, 0, stream>>>(sb, SKVT_);
            if (i == 1)
                k_attn_mean<<<8192, 256, 0, stream>>>(sb, attnw + (size_t)b * SQ_ * SKVT_);
            gemm(stream, sb, SKVT_, (long long)SQ_ * SKVT_,
                 vb + (size_t)b * SKVT_ * D_, D_, HD_,
                 ctx + (size_t)b * SQ_ * D_, D_, HD_,
                 H_, SQ_, HD_, SKVT_, 1.f, nullptr, true);
        }
        gemm(stream, ctx, D_, 0, caoutw + (size_t)i * D_ * D_, D_, 0, ob, D_, 0,
             1, B_ * SQ_, D_, D_, 1.f, caoutb + i * D_, false);
        k_add<<<2048, 256, 0, stream>>>(xb, ob);
    }

    // --- agreement ---
    gemm(stream, summ, NR_ * D_, 0, agw1, NR_ * D_, 0, agh, 2 * D_, 0,
         1, B_, 2 * D_, NR_ * D_, 1.f, agb1, false);
    k_gelu<<<16, 256, 0, stream>>>(agh, B_ * 2 * D_);
    gemm(stream, agh, 2 * D_, 0, agw2, 2 * D_, 0, ago, D_, 0,
         1, B_, D_, 2 * D_, 1.f, agb2, false);
    k_rmsnorm<<<B_, 256, 0, stream>>>(ago, agnw, agr);
    k_add_bcast<<<8192, 256, 0, stream>>>(xb, agr);

    // --- generator layers x6 ---
    for (int l = 0; l < NL_; ++l) {
        const size_t woff = (size_t)l * D_ * D_;
        const size_t foff = (size_t)l * FF_ * D_;
        k_rmsnorm<<<B_ * SQ_, 256, 0, stream>>>(xb, n1w + l * D_, hb);
        gemm(stream, hb, D_, 0, wq + woff, D_, 0, qb, D_, 0, 1, B_ * SQ_, D_, D_, 1.f, nullptr, false);
        gemm(stream, hb, D_, 0, wk + woff, D_, 0, kb, D_, 0, 1, B_ * SQ_, D_, D_, 1.f, nullptr, false);
        gemm(stream, hb, D_, 0, wv + woff, D_, 0, vb, D_, 0, 1, B_ * SQ_, D_, D_, 1.f, nullptr, false);
        k_rope<<<4096, 256, 0, stream>>>(qb, kb);
        for (int b = 0; b < B_; ++b) {
            gemm(stream, qb + (size_t)b * SQ_ * D_, D_, HD_,
                 kb + (size_t)b * SQ_ * D_, D_, HD_,
                 sb, SQ_, (long long)SQ_ * SQ_,
                 H_, SQ_, SQ_, HD_, iscale, nullptr, false);
            k_softmax<<<H_ * SQ_, 256, 0, stream>>>(sb, SQ_);
            gemm(stream, sb, SQ_, (long long)SQ_ * SQ_,
                 vb + (size_t)b * SQ_ * D_, D_, HD_,
                 ctx + (size_t)b * SQ_ * D_, D_, HD_,
                 H_, SQ_, HD_, SQ_, 1.f, nullptr, true);
        }
        gemm(stream, ctx, D_, 0, wo + woff, D_, 0, ob, D_, 0, 1, B_ * SQ_, D_, D_, 1.f, nullptr, false);
        k_add<<<2048, 256, 0, stream>>>(xb, ob);

        k_rmsnorm<<<B_ * SQ_, 256, 0, stream>>>(xb, n2w + l * D_, hb);
        gemm(stream, hb, D_, 0, wg + foff, D_, 0, ffg, FF_, 0, 1, B_ * SQ_, FF_, D_, 1.f, nullptr, false);
        gemm(stream, hb, D_, 0, wu + foff, D_, 0, ffu, FF_, 0, 1, B_ * SQ_, FF_, D_, 1.f, nullptr, false);
        k_silu_mul<<<32768, 256, 0, stream>>>(ffg, ffu);
        gemm(stream, ffg, FF_, 0, wdn + foff, FF_, 0, ob, D_, 0, 1, B_ * SQ_, D_, FF_, 1.f, nullptr, false);
        k_add<<<2048, 256, 0, stream>>>(xb, ob);
    }

    // --- final: norm, logits, meta ---
    k_rmsnorm<<<B_ * SQ_, 256, 0, stream>>>(xb, gnw, hb);
    gemm(stream, hb, D_, 0, lmw, D_, 0, logits, VOCAB_, 0,
         1, B_ * SQ_, VOCAB_, D_, 1.f, nullptr, false);
    k_meanpool<<<8, 256, 0, stream>>>(hb, pooled);
    gemm(stream, pooled, D_, 0, mw1, D_, 0, mbuf, 256, 0,
         1, B_, 256, D_, 1.f, mb1, false);
    k_gelu<<<2, 256, 0, stream>>>(mbuf, B_ * 256);
    gemm(stream, mbuf, 256, 0, mw2, 256, 0, meta, 3, 0,
         1, B_, 3, 256, 1.f, mb2, false);
}

// Round 2
// 8395.683 us; speedup vs baseline: 2.4535x; 2.4535x over previous
//
#include <hip/hip_runtime.h>
#include <math.h>

// Model dims (fixed by the reference)
#define D_     1024
#define H_     8
#define HD_    128
#define NR_    4
#define B_     2
#define SQ_    1024
#define SKV_   512
#define SKVT_  2048
#define VOCAB_ 32000
#define NL_    6
#define FF_    4096
#define EPS_   1e-6f

typedef unsigned short u16;
typedef __attribute__((ext_vector_type(8))) __bf16 bf16x8;
typedef __attribute__((ext_vector_type(4))) float f32x4;

// ---------------- bf16 split helpers (RNE) ----------------
__device__ __forceinline__ u16 f2bf_rn(float f) {
    unsigned u = __float_as_uint(f);
    unsigned r = (u + 0x7FFFu + ((u >> 16) & 1u)) >> 16;
    return (u16)r;
}
__device__ __forceinline__ float bf2f(u16 h) {
    return __uint_as_float(((unsigned)h) << 16);
}
__device__ __forceinline__ void splitf(float v, u16& h, u16& l) {
    h = f2bf_rn(v);
    l = f2bf_rn(v - bf2f(h));
}

// async global->LDS, 16B per lane, wave-uniform LDS base
__device__ __forceinline__ void glds16(const u16* g, const u16* l) {
    __builtin_amdgcn_global_load_lds(
        (const __attribute__((address_space(1))) void*)g,
        (__attribute__((address_space(3))) void*)l,
        16, 0, 0);
}

// ===========================================================================
// MFMA split-bf16 GEMM.
//   C[z] = scale * A[z] @ B[z]^T + bias   (B given as [N][K] row-major "weight layout")
//   A,B are hi/lo bf16 pairs. 3 MFMA passes: Ah*Bh + Al*Bh + Ah*Bl.
//   Requires M%128==0, N%128==0, K%32==0. z = zb*ZH+zh with separate strides.
//   CMODE: 0 = fp32 C, 1 = bf16-pair C, 2 = bf16-pair C transposed (C[n][m]).
// Structure: m97 ladder step-3 (128x128 tile, BK=32, 4 waves, global_load_lds w16,
// slab-major LDS so ds_read_b128 is conflict-free).
// ===========================================================================
enum { CM_F32 = 0, CM_PAIR = 1, CM_PAIRT = 2 };

template<int CMODE>
__global__ __launch_bounds__(256, 2)
void k_gemm_bf(const u16* __restrict__ Ah, const u16* __restrict__ Al,
               int lda, long long sAb, long long sAh,
               const u16* __restrict__ Bh, const u16* __restrict__ Bl,
               int ldb, long long sBb, long long sBh,
               float* __restrict__ Cf, u16* __restrict__ Ch, u16* __restrict__ Cl,
               int ldc, long long sCb, long long sCh,
               int K, int ZH, float scale, const float* __restrict__ bias)
{
    // 4 tiles (Ah, Al, Bh, Bl), each [4 slabs][128 rows][8 bf16 = 16B] = 8KB
    __shared__ u16 lds[16384];

    const int z  = blockIdx.z;
    const int zb = z / ZH, zh = z - zb * ZH;
    const long long offA = zb * sAb + zh * sAh;
    const long long offB = zb * sBb + zh * sBh;
    const long long offC = zb * sCb + zh * sCh;

    const int m0 = blockIdx.y << 7, n0 = blockIdx.x << 7;
    const int tid = threadIdx.x, lane = tid & 63, w = tid >> 6;
    const int wr = w >> 1, wc = w & 1;

    const u16* pAh = Ah + offA; const u16* pAl = Al + offA;
    const u16* pBh = Bh + offB; const u16* pBl = Bl + offB;

    f32x4 acc[4][4];
#pragma unroll
    for (int i = 0; i < 4; ++i)
#pragma unroll
        for (int j = 0; j < 4; ++j) acc[i][j] = (f32x4){0.f, 0.f, 0.f, 0.f};

    const int ks = lane >> 4, lr16 = lane & 15;

    for (int k0 = 0; k0 < K; k0 += 32) {
        // ---- stage: 8 chunks of 1KB per tile; chunk = slab*2+half ----
#pragma unroll
        for (int c = 0; c < 2; ++c) {
            const int chunk = w * 2 + c;
            const int slab = chunk >> 1, hf = chunk & 1;
            const int row = hf * 64 + lane;
            const int lbase = (slab * 128 + hf * 64) * 8;   // u16 index, wave-uniform
            const long long ga = (long long)(m0 + row) * lda + (k0 + slab * 8);
            const long long gb = (long long)(n0 + row) * ldb + (k0 + slab * 8);
            glds16(pAh + ga, &lds[lbase]);
            glds16(pAl + ga, &lds[4096 + lbase]);
            glds16(pBh + gb, &lds[8192 + lbase]);
            glds16(pBl + gb, &lds[12288 + lbase]);
        }
        __syncthreads();

        // ---- fragments + MFMA ----
        bf16x8 bh[4], bl[4];
#pragma unroll
        for (int nj = 0; nj < 4; ++nj) {
            const int off = (ks * 128 + wc * 64 + nj * 16 + lr16) * 8;
            bh[nj] = *(const bf16x8*)&lds[8192 + off];
            bl[nj] = *(const bf16x8*)&lds[12288 + off];
        }
#pragma unroll
        for (int mi = 0; mi < 4; ++mi) {
            const int off = (ks * 128 + wr * 64 + mi * 16 + lr16) * 8;
            bf16x8 ah = *(const bf16x8*)&lds[off];
            bf16x8 al = *(const bf16x8*)&lds[4096 + off];
#pragma unroll
            for (int nj = 0; nj < 4; ++nj) {
                acc[mi][nj] = __builtin_amdgcn_mfma_f32_16x16x32_bf16(ah, bh[nj], acc[mi][nj], 0, 0, 0);
                acc[mi][nj] = __builtin_amdgcn_mfma_f32_16x16x32_bf16(al, bh[nj], acc[mi][nj], 0, 0, 0);
                acc[mi][nj] = __builtin_amdgcn_mfma_f32_16x16x32_bf16(ah, bl[nj], acc[mi][nj], 0, 0, 0);
            }
        }
        __syncthreads();
    }

    // ---- epilogue: C[row=m][col=n], m = wr*64+mi*16+(lane>>4)*4+j, n = wc*64+nj*16+(lane&15)
#pragma unroll
    for (int mi = 0; mi < 4; ++mi) {
#pragma unroll
        for (int nj = 0; nj < 4; ++nj) {
#pragma unroll
            for (int j = 0; j < 4; ++j) {
                const int row = m0 + wr * 64 + mi * 16 + (lane >> 4) * 4 + j;
                const int col = n0 + wc * 64 + nj * 16 + lr16;
                float v = acc[mi][nj][j] * scale;
                if (bias) v += bias[col];
                if (CMODE == CM_F32) {
                    Cf[offC + (long long)row * ldc + col] = v;
                } else {
                    u16 h, l;
                    splitf(v, h, l);
                    const long long idx = (CMODE == CM_PAIR)
                        ? offC + (long long)row * ldc + col
                        : offC + (long long)col * ldc + row;
                    Ch[idx] = h; Cl[idx] = l;
                }
            }
        }
    }
}

// ---------------------------------------------------------------------------
// fp32 fallback GEMM (round-1 kernel, unchanged semantics)
// ---------------------------------------------------------------------------
template<bool BTRANS>
__global__ __launch_bounds__(256)
void k_gemm(const float* __restrict__ A, int lda, long long sA,
            const float* __restrict__ B, int ldb, long long sB,
            float* __restrict__ C, int ldc, long long sC,
            int M, int N, int K, float scale, const float* __restrict__ bias)
{
    __shared__ float As[16][128];
    __shared__ float Bs[16][128];

    const int z = blockIdx.z;
    A += (long long)z * sA;
    B += (long long)z * sB;
    C += (long long)z * sC;

    const int m0 = blockIdx.y * 128;
    const int n0 = blockIdx.x * 128;
    const int tid = threadIdx.x;
    const int tm = tid >> 4;
    const int tn = tid & 15;
    const int lr = tid >> 2;
    const int lc = (tid & 3) << 2;

    float acc[8][8];
#pragma unroll
    for (int i = 0; i < 8; ++i)
#pragma unroll
        for (int j = 0; j < 8; ++j) acc[i][j] = 0.f;

    for (int k0 = 0; k0 < K; k0 += 16) {
#pragma unroll
        for (int r = 0; r < 2; ++r) {
            int m = lr + r * 64;
            float4 av = make_float4(0.f, 0.f, 0.f, 0.f);
            if (m0 + m < M)
                av = *(const float4*)(A + (long long)(m0 + m) * lda + (k0 + lc));
            As[lc + 0][m] = av.x; As[lc + 1][m] = av.y;
            As[lc + 2][m] = av.z; As[lc + 3][m] = av.w;
        }
        if (!BTRANS) {
#pragma unroll
            for (int r = 0; r < 2; ++r) {
                int n = lr + r * 64;
                float4 bv = make_float4(0.f, 0.f, 0.f, 0.f);
                if (n0 + n < N)
                    bv = *(const float4*)(B + (long long)(n0 + n) * ldb + (k0 + lc));
                Bs[lc + 0][n] = bv.x; Bs[lc + 1][n] = bv.y;
                Bs[lc + 2][n] = bv.z; Bs[lc + 3][n] = bv.w;
            }
        } else {
            int kk = tid >> 5;
            int nn = (tid & 31) << 2;
#pragma unroll
            for (int r = 0; r < 2; ++r) {
                int k = kk + r * 8;
                float4 bv = make_float4(0.f, 0.f, 0.f, 0.f);
                if (n0 + nn < N)
                    bv = *(const float4*)(B + (long long)(k0 + k) * ldb + (n0 + nn));
                *(float4*)&Bs[k][nn] = bv;
            }
        }
        __syncthreads();

#pragma unroll
        for (int kk = 0; kk < 16; ++kk) {
            float a[8], b[8];
            *(float4*)&a[0] = *(const float4*)&As[kk][tm * 8];
            *(float4*)&a[4] = *(const float4*)&As[kk][tm * 8 + 4];
            *(float4*)&b[0] = *(const float4*)&Bs[kk][tn * 8];
            *(float4*)&b[4] = *(const float4*)&Bs[kk][tn * 8 + 4];
#pragma unroll
            for (int i = 0; i < 8; ++i)
#pragma unroll
                for (int j = 0; j < 8; ++j)
                    acc[i][j] = fmaf(a[i], b[j], acc[i][j]);
        }
        __syncthreads();
    }

#pragma unroll
    for (int i = 0; i < 8; ++i) {
        int m = m0 + tm * 8 + i;
        if (m < M) {
#pragma unroll
            for (int j = 0; j < 8; ++j) {
                int n = n0 + tn * 8 + j;
                if (n < N) {
                    float v = acc[i][j] * scale;
                    if (bias) v += bias[n];
                    C[(long long)m * ldc + n] = v;
                }
            }
        }
    }
}

// ---------------------------------------------------------------------------
// RMSNorm, rows of 1024. Writes fp32 (if yf) and/or bf16 pair (if yh).
// ---------------------------------------------------------------------------
__global__ __launch_bounds__(256)
void k_rmsnorm(const float* __restrict__ x, const float* __restrict__ w,
               float* __restrict__ yf, u16* __restrict__ yh, u16* __restrict__ yl)
{
    long long row = blockIdx.x;
    const float* xr = x + row * D_;
    int tid = threadIdx.x;

    float4 v = *(const float4*)(xr + tid * 4);
    float ss = v.x * v.x + v.y * v.y + v.z * v.z + v.w * v.w;
#pragma unroll
    for (int off = 32; off >= 1; off >>= 1) ss += __shfl_xor(ss, off);
    __shared__ float red[4];
    if ((tid & 63) == 0) red[tid >> 6] = ss;
    __syncthreads();
    float tot = red[0] + red[1] + red[2] + red[3];
    float sc = 1.0f / sqrtf(tot * (1.0f / D_) + EPS_);

    float4 wv = *(const float4*)(w + tid * 4);
    float o[4];
    o[0] = v.x * sc * wv.x; o[1] = v.y * sc * wv.y;
    o[2] = v.z * sc * wv.z; o[3] = v.w * sc * wv.w;
    if (yf) *(float4*)(yf + row * D_ + tid * 4) = make_float4(o[0], o[1], o[2], o[3]);
    if (yh) {
        u16 h[4], l[4];
#pragma unroll
        for (int i = 0; i < 4; ++i) splitf(o[i], h[i], l[i]);
        uint2 ph = make_uint2((unsigned)h[0] | ((unsigned)h[1] << 16),
                              (unsigned)h[2] | ((unsigned)h[3] << 16));
        uint2 pl = make_uint2((unsigned)l[0] | ((unsigned)l[1] << 16),
                              (unsigned)l[2] | ((unsigned)l[3] << 16));
        ((uint2*)(yh + row * D_))[tid] = ph;
        ((uint2*)(yl + row * D_))[tid] = pl;
    }
}

// ---------------------------------------------------------------------------
// Row softmax: fp32 in-place (if wf32), bf16 pair out (if Ph).
// ---------------------------------------------------------------------------
__global__ __launch_bounds__(256)
void k_softmax(float* __restrict__ S, u16* __restrict__ Ph, u16* __restrict__ Pl,
               int N, int wf32)
{
    __shared__ float buf[2048];
    __shared__ float red[4];
    long long row = blockIdx.x;
    float* p = S + row * (long long)N;
    int tid = threadIdx.x;

    float mx = -1e30f;
    for (int i = tid; i < N; i += 256) { float v = p[i]; buf[i] = v; mx = fmaxf(mx, v); }
#pragma unroll
    for (int off = 32; off >= 1; off >>= 1) mx = fmaxf(mx, __shfl_xor(mx, off));
    if ((tid & 63) == 0) red[tid >> 6] = mx;
    __syncthreads();
    mx = fmaxf(fmaxf(red[0], red[1]), fmaxf(red[2], red[3]));

    float sum = 0.f;
    for (int i = tid; i < N; i += 256) { float e = __expf(buf[i] - mx); buf[i] = e; sum += e; }
#pragma unroll
    for (int off = 32; off >= 1; off >>= 1) sum += __shfl_xor(sum, off);
    __syncthreads();
    if ((tid & 63) == 0) red[tid >> 6] = sum;
    __syncthreads();
    sum = red[0] + red[1] + red[2] + red[3];
    float inv = 1.0f / sum;
    for (int i = tid; i < N; i += 256) {
        float pv = buf[i] * inv;
        if (wf32) p[i] = pv;
        if (Ph) {
            u16 h, l;
            splitf(pv, h, l);
            Ph[row * (long long)N + i] = h;
            Pl[row * (long long)N + i] = l;
        }
    }
}

// ---------------------------------------------------------------------------
// weighted KV: fp32 out (old path) or bf16 pair (mfma path). 4 elems/thread.
// ---------------------------------------------------------------------------
__global__ void k_weighted_kv(const float* __restrict__ rh,
                              const float* __restrict__ conf,
                              float* __restrict__ kvf,
                              u16* __restrict__ kvh, u16* __restrict__ kvl)
{
    int i4 = blockIdx.x * 256 + threadIdx.x;       // total (B*NR*SKV*D)/4 = 2^20
    int d4 = i4 & 255;
    int s  = (i4 >> 8) & (SKV_ - 1);
    int n  = (i4 >> 17) & (NR_ - 1);
    int b  = i4 >> 19;
    float c = conf[b * NR_ + n];
    float4 v = ((const float4*)(rh + (((long long)(n * B_ + b) * SKV_ + s) * D_)))[d4];
    v.x *= c; v.y *= c; v.z *= c; v.w *= c;
    if (kvf) ((float4*)kvf)[i4] = v;
    if (kvh) {
        u16 h[4], l[4];
        splitf(v.x, h[0], l[0]); splitf(v.y, h[1], l[1]);
        splitf(v.z, h[2], l[2]); splitf(v.w, h[3], l[3]);
        ((uint2*)kvh)[i4] = make_uint2((unsigned)h[0] | ((unsigned)h[1] << 16),
                                       (unsigned)h[2] | ((unsigned)h[3] << 16));
        ((uint2*)kvl)[i4] = make_uint2((unsigned)l[0] | ((unsigned)l[1] << 16),
                                       (unsigned)l[2] | ((unsigned)l[3] << 16));
    }
}

// summaries[b, n*D+d] = mean_s rh[n,b,s,d]
__global__ void k_summaries(const float* __restrict__ rh, float* __restrict__ sm)
{
    int idx = blockIdx.x * 256 + threadIdx.x;      // B*NR*D = 8192
    int d = idx & (D_ - 1);
    int n = (idx >> 10) & (NR_ - 1);
    int b = idx >> 12;
    const float* p = rh + ((long long)(n * B_ + b) * SKV_) * D_ + d;
    float s = 0.f;
    for (int t = 0; t < SKV_; ++t) s += p[(long long)t * D_];
    sm[idx] = s * (1.0f / SKV_);
}

// out[m,n] = mean_h S[h,m,n]
__global__ void k_attn_mean(const float* __restrict__ S, float* __restrict__ O)
{
    int idx = blockIdx.x * 256 + threadIdx.x;      // SQ*SKVT = 2^21
    float s = 0.f;
#pragma unroll
    for (int h = 0; h < H_; ++h) s += S[(long long)h * SQ_ * SKVT_ + idx];
    O[idx] = s * (1.0f / H_);
}

// RoPE: fp32 in-place (old path, qh==null) OR write bf16 pairs (mfma path)
__global__ void k_rope(float* __restrict__ q, float* __restrict__ k,
                       u16* __restrict__ qh, u16* __restrict__ ql,
                       u16* __restrict__ kh, u16* __restrict__ kl)
{
    int idx = blockIdx.x * 256 + threadIdx.x;      // B*SQ*H*64 = 2^20
    int j = idx & 63;
    int h = (idx >> 6) & (H_ - 1);
    int s = (idx >> 9) & (SQ_ - 1);
    int b = idx >> 19;
    float inv = __expf(-9.210340371976184f * (float)j * (1.0f / 64.0f));
    float ang = (float)s * inv;
    float sn, cs;
    __sincosf(ang, &sn, &cs);
    long long base = ((long long)(b * SQ_ + s)) * D_ + h * HD_ + j;
    float q1 = q[base], q2 = q[base + 64];
    float qo1 = q1 * cs - q2 * sn;
    float qo2 = q2 * cs + q1 * sn;
    float k1 = k[base], k2 = k[base + 64];
    float ko1 = k1 * cs - k2 * sn;
    float ko2 = k2 * cs + k1 * sn;
    if (qh) {
        u16 h0, l0;
        splitf(qo1, h0, l0); qh[base] = h0;      ql[base] = l0;
        splitf(qo2, h0, l0); qh[base + 64] = h0; ql[base + 64] = l0;
        splitf(ko1, h0, l0); kh[base] = h0;      kl[base] = l0;
        splitf(ko2, h0, l0); kh[base + 64] = h0; kl[base + 64] = l0;
    } else {
        q[base] = qo1; q[base + 64] = qo2;
        k[base] = ko1; k[base + 64] = ko2;
    }
}

// y += a
__global__ void k_add(float* __restrict__ y, const float* __restrict__ a)
{
    int i = blockIdx.x * 256 + threadIdx.x;
    float4 v = *(const float4*)(y + i * 4);
    float4 u = *(const float4*)(a + i * 4);
    v.x += u.x; v.y += u.y; v.z += u.z; v.w += u.w;
    *(float4*)(y + i * 4) = v;
}

// x[b,s,:] += ag[b,:]
__global__ void k_add_bcast(float* __restrict__ x, const float* __restrict__ ag)
{
    int idx = blockIdx.x * 256 + threadIdx.x;
    int d = idx & (D_ - 1);
    int b = idx >> 20;
    x[idx] += ag[b * D_ + d];
}

__global__ void k_gelu(float* __restrict__ v, int n)
{
    int i = blockIdx.x * 256 + threadIdx.x;
    if (i < n) {
        float x = v[i];
        v[i] = 0.5f * x * (1.0f + erff(x * 0.7071067811865476f));
    }
}

// silu(g)*u -> fp32 in place (old) or bf16 pair (mfma)
__global__ void k_silu_mul(float* __restrict__ g, const float* __restrict__ u,
                           u16* __restrict__ fh, u16* __restrict__ fl)
{
    int i = blockIdx.x * 256 + threadIdx.x;
    float x = g[i];
    float r = (x / (1.0f + __expf(-x))) * u[i];
    if (fh) {
        u16 h, l;
        splitf(r, h, l);
        fh[i] = h; fl[i] = l;
    } else {
        g[i] = r;
    }
}

__global__ void k_meanpool(const float* __restrict__ h, float* __restrict__ p)
{
    int idx = blockIdx.x * 256 + threadIdx.x;
    int d = idx & (D_ - 1);
    int b = idx >> 10;
    const float* r = h + ((long long)b * SQ_) * D_ + d;
    float s = 0.f;
    for (int t = 0; t < SQ_; ++t) s += r[(long long)t * D_];
    p[idx] = s * (1.0f / SQ_);
}

// fp32 -> bf16 hi/lo split, 4 elems/thread
__global__ void k_split(const float* __restrict__ x, u16* __restrict__ h,
                        u16* __restrict__ l, int n4)
{
    int i = blockIdx.x * 256 + threadIdx.x;
    if (i < n4) {
        float4 v = ((const float4*)x)[i];
        u16 hh[4], ll[4];
        splitf(v.x, hh[0], ll[0]); splitf(v.y, hh[1], ll[1]);
        splitf(v.z, hh[2], ll[2]); splitf(v.w, hh[3], ll[3]);
        ((uint2*)h)[i] = make_uint2((unsigned)hh[0] | ((unsigned)hh[1] << 16),
                                    (unsigned)hh[2] | ((unsigned)hh[3] << 16));
        ((uint2*)l)[i] = make_uint2((unsigned)ll[0] | ((unsigned)ll[1] << 16),
                                    (unsigned)ll[2] | ((unsigned)ll[3] << 16));
    }
}

// ---------------------------------------------------------------------------
// host helpers
// ---------------------------------------------------------------------------
static void gemm(hipStream_t st,
                 const float* A, int lda, long long sA,
                 const float* B, int ldb, long long sB,
                 float* C, int ldc, long long sC,
                 int Z, int M, int N, int K, float scale, const float* bias,
                 bool btrans)
{
    dim3 g((N + 127) / 128, (M + 127) / 128, Z);
    if (btrans)
        k_gemm<true><<<g, 256, 0, st>>>(A, lda, sA, B, ldb, sB, C, ldc, sC, M, N, K, scale, bias);
    else
        k_gemm<false><<<g, 256, 0, st>>>(A, lda, sA, B, ldb, sB, C, ldc, sC, M, N, K, scale, bias);
}

struct BfMat { const u16* h; const u16* l; int ld; long long sb, sh; };

static void gemm_bf(hipStream_t st, int cmode,
                    BfMat A, BfMat B,
                    float* Cf, u16* Ch, u16* Cl, int ldc, long long sCb, long long sCh,
                    int M, int N, int K, int Z, int ZH, float scale, const float* bias)
{
    dim3 g(N / 128, M / 128, Z);
    if (cmode == CM_F32)
        k_gemm_bf<CM_F32><<<g, 256, 0, st>>>(A.h, A.l, A.ld, A.sb, A.sh,
                                             B.h, B.l, B.ld, B.sb, B.sh,
                                             Cf, Ch, Cl, ldc, sCb, sCh, K, ZH, scale, bias);
    else if (cmode == CM_PAIR)
        k_gemm_bf<CM_PAIR><<<g, 256, 0, st>>>(A.h, A.l, A.ld, A.sb, A.sh,
                                              B.h, B.l, B.ld, B.sb, B.sh,
                                              Cf, Ch, Cl, ldc, sCb, sCh, K, ZH, scale, bias);
    else
        k_gemm_bf<CM_PAIRT><<<g, 256, 0, st>>>(A.h, A.l, A.ld, A.sb, A.sh,
                                               B.h, B.l, B.ld, B.sb, B.sh,
                                               Cf, Ch, Cl, ldc, sCb, sCh, K, ZH, scale, bias);
}

static void split_w(hipStream_t st, const float* w, u16* h, u16* l, long long n)
{
    int n4 = (int)(n >> 2);
    k_split<<<(n4 + 255) / 256, 256, 0, st>>>(w, h, l, n4);
}

// ===========================================================================
extern "C" void kernel_launch(void* const* d_in, const int* in_sizes, int n_in,
                              void* d_out, int out_size, void* d_ws, size_t ws_size,
                              hipStream_t stream)
{
    const float* rh     = (const float*)d_in[0];
    const float* conf   = (const float*)d_in[1];
    const float* qh     = (const float*)d_in[3];
    const float* cainw  = (const float*)d_in[4];
    const float* cainb  = (const float*)d_in[5];
    const float* caoutw = (const float*)d_in[6];
    const float* caoutb = (const float*)d_in[7];
    const float* cnorm  = (const float*)d_in[8];
    const float* agw1   = (const float*)d_in[9];
    const float* agb1   = (const float*)d_in[10];
    const float* agw2   = (const float*)d_in[11];
    const float* agb2   = (const float*)d_in[12];
    const float* agnw   = (const float*)d_in[13];
    const float* n1w    = (const float*)d_in[14];
    const float* wq     = (const float*)d_in[15];
    const float* wk     = (const float*)d_in[16];
    const float* wv     = (const float*)d_in[17];
    const float* wo     = (const float*)d_in[18];
    const float* n2w    = (const float*)d_in[19];
    const float* wg     = (const float*)d_in[20];
    const float* wu     = (const float*)d_in[21];
    const float* wdn    = (const float*)d_in[22];
    const float* gnw    = (const float*)d_in[23];
    const float* lmw    = (const float*)d_in[24];
    const float* mw1    = (const float*)d_in[25];
    const float* mb1    = (const float*)d_in[26];
    const float* mw2    = (const float*)d_in[27];
    const float* mb2    = (const float*)d_in[28];

    float* out    = (float*)d_out;
    float* logits = out;
    float* meta   = out + 65536000;
    float* attnw  = out + 65536006;

    const float iscale = 0.08838834764831845f;   // 1/sqrt(128)
    const size_t MFMA_WS = 276905984ULL;

    if (ws_size >= MFMA_WS) {
        // =================== MFMA split-bf16 path ===================
        char* base = (char*)d_ws;
        float* xb    = (float*)(base + 0);            // 2,097,152 f
        float* qb    = (float*)(base + 8388608);
        float* kb    = (float*)(base + 16777216);
        float* ob    = (float*)(base + 25165824);
        float* R1    = (float*)(base + 33554432);     // 16,777,216 f: sb | ffg+ffu
        float* sml   = (float*)(base + 100663296);    // small fp32
        u16* akvh = (u16*)(base + 100745216);         // 4,194,304 u16 each
        u16* akvl = (u16*)(base + 109133824);
        u16* hbh  = (u16*)(base + 117522432);         // 2,097,152
        u16* hbl  = (u16*)(base + 121716736);
        u16* qph  = (u16*)(base + 125911040);         // 2,097,152
        u16* qpl  = (u16*)(base + 130105344);
        u16* kph  = (u16*)(base + 134299648);         // 4,194,304
        u16* kpl  = (u16*)(base + 142688256);
        u16* vth  = (u16*)(base + 151076864);         // 4,194,304
        u16* vtl  = (u16*)(base + 159465472);
        u16* ctxh = (u16*)(base + 167854080);         // 2,097,152
        u16* ctxl = (u16*)(base + 172048384);
        u16* R2h  = (u16*)(base + 176242688);         // p_h / ff_h
        u16* R2l  = (u16*)(base + 209797120);         // p_l / ff_l
        u16* wsh  = (u16*)(base + 243351552);         // 8,388,608 u16
        u16* wsl  = (u16*)(base + 260128768);

        float* sb  = R1;
        float* ffg = R1;
        float* ffu = R1 + 8388608;
        u16* ph = R2h; u16* pl = R2l;
        u16* ffh = R2h; u16* ffl = R2h + 16777216 / 2 * 0 + 16777216; // ff_l right after ff_h inside R2h..; see note
        // ff pair: place hi at R2h, lo at R2l (both have 16,777,216-elem capacity)
        ffh = R2h; ffl = R2l;

        float* summ   = sml;
        float* agh    = summ + 8192;
        float* ago    = agh + 4096;
        float* agr    = ago + 2048;
        float* pooled = agr + 2048;
        float* mbuf   = pooled + 2048;

        // --- stage 0 ---
        k_weighted_kv<<<4096, 256, 0, stream>>>(rh, conf, nullptr, akvh, akvl);
        k_summaries<<<32, 256, 0, stream>>>(rh, summ);
        hipMemcpyAsync(xb, qh, (size_t)2097152 * 4, hipMemcpyDeviceToDevice, stream);

        BfMat Ahb  = {hbh, hbl, D_, 0, 0};
        BfMat Akv  = {akvh, akvl, D_, 0, 0};
        BfMat Wscr = {wsh, wsl, D_, 0, 0};

        // --- cross-attention x2 ---
        for (int i = 0; i < 2; ++i) {
            const float* inw = cainw + (size_t)i * 3 * D_ * D_;
            const float* inb = cainb + (size_t)i * 3 * D_;
            k_rmsnorm<<<B_ * SQ_, 256, 0, stream>>>(xb, cnorm + i * D_, nullptr, hbh, hbl);
            // q
            split_w(stream, inw, wsh, wsl, 1048576);
            gemm_bf(stream, CM_PAIR, Ahb, Wscr, nullptr, qph, qpl, D_, 0, 0,
                    B_ * SQ_, D_, D_, 1, 1, 1.f, inb);
            // k
            split_w(stream, inw + 1048576, wsh, wsl, 1048576);
            gemm_bf(stream, CM_PAIR, Akv, Wscr, nullptr, kph, kpl, D_, 0, 0,
                    B_ * SKVT_, D_, D_, 1, 1, 1.f, inb + D_);
            // v -> transposed [D][B*SKVT]
            split_w(stream, inw + 2097152, wsh, wsl, 1048576);
            gemm_bf(stream, CM_PAIRT, Akv, Wscr, nullptr, vth, vtl, B_ * SKVT_, 0, 0,
                    B_ * SKVT_, D_, D_, 1, 1, 1.f, inb + 2 * D_);

            for (int b = 0; b < B_; ++b) {
                // QK^T: z = head
                BfMat Aq = {qph + (size_t)b * SQ_ * D_, qpl + (size_t)b * SQ_ * D_, D_, 0, HD_};
                BfMat Bk = {kph + (size_t)b * SKVT_ * D_, kpl + (size_t)b * SKVT_ * D_, D_, 0, HD_};
                gemm_bf(stream, CM_F32, Aq, Bk, sb, nullptr, nullptr,
                        SKVT_, 0, (long long)SQ_ * SKVT_,
                        SQ_, SKVT_, HD_, H_, H_, iscale, nullptr);
                k_softmax<<<H_ * SQ_, 256, 0, stream>>>(sb, ph, pl, SKVT_, (i == 1) ? 1 : 0);
                if (i == 1)
                    k_attn_mean<<<8192, 256, 0, stream>>>(sb, attnw + (size_t)b * SQ_ * SKVT_);
                // PV: A=p [h][s][kv], B=vT [D][B*SKVT]
                BfMat Ap = {ph, pl, SKVT_, 0, (long long)SQ_ * SKVT_};
                BfMat Bv = {vth + (size_t)b * SKVT_, vtl + (size_t)b * SKVT_,
                            B_ * SKVT_, 0, (long long)HD_ * B_ * SKVT_};
                gemm_bf(stream, CM_PAIR, Ap, Bv, nullptr,
                        ctxh + (size_t)b * SQ_ * D_, ctxl + (size_t)b * SQ_ * D_,
                        D_, 0, HD_, SQ_, HD_, SKVT_, H_, H_, 1.f, nullptr);
            }
            // out proj
            split_w(stream, caoutw + (size_t)i * D_ * D_, wsh, wsl, 1048576);
            BfMat Actx = {ctxh, ctxl, D_, 0, 0};
            gemm_bf(stream, CM_F32, Actx, Wscr, ob, nullptr, nullptr, D_, 0, 0,
                    B_ * SQ_, D_, D_, 1, 1, 1.f, caoutb + i * D_);
            k_add<<<2048, 256, 0, stream>>>(xb, ob);
        }

        // --- agreement (tiny, fp32 path) ---
        gemm(stream, summ, NR_ * D_, 0, agw1, NR_ * D_, 0, agh, 2 * D_, 0,
             1, B_, 2 * D_, NR_ * D_, 1.f, agb1, false);
        k_gelu<<<16, 256, 0, stream>>>(agh, B_ * 2 * D_);
        gemm(stream, agh, 2 * D_, 0, agw2, 2 * D_, 0, ago, D_, 0,
             1, B_, D_, 2 * D_, 1.f, agb2, false);
        k_rmsnorm<<<B_, 256, 0, stream>>>(ago, agnw, agr, nullptr, nullptr);
        k_add_bcast<<<8192, 256, 0, stream>>>(xb, agr);

        // --- generator layers x6 ---
        for (int l = 0; l < NL_; ++l) {
            const size_t woff = (size_t)l * D_ * D_;
            const size_t foff = (size_t)l * FF_ * D_;
            k_rmsnorm<<<B_ * SQ_, 256, 0, stream>>>(xb, n1w + l * D_, nullptr, hbh, hbl);
            split_w(stream, wq + woff, wsh, wsl, 1048576);
            gemm_bf(stream, CM_F32, Ahb, Wscr, qb, nullptr, nullptr, D_, 0, 0,
                    B_ * SQ_, D_, D_, 1, 1, 1.f, nullptr);
            split_w(stream, wk + woff, wsh, wsl, 1048576);
            gemm_bf(stream, CM_F32, Ahb, Wscr, kb, nullptr, nullptr, D_, 0, 0,
                    B_ * SQ_, D_, D_, 1, 1, 1.f, nullptr);
            split_w(stream, wv + woff, wsh, wsl, 1048576);
            gemm_bf(stream, CM_PAIRT, Ahb, Wscr, nullptr, vth, vtl, B_ * SQ_, 0, 0,
                    B_ * SQ_, D_, D_, 1, 1, 1.f, nullptr);
            k_rope<<<4096, 256, 0, stream>>>(qb, kb, qph, qpl, kph, kpl);

            // QK^T merged over batch+head: Z=16, ZH=8
            {
                BfMat Aq = {qph, qpl, D_, (long long)SQ_ * D_, HD_};
                BfMat Bk = {kph, kpl, D_, (long long)SQ_ * D_, HD_};
                gemm_bf(stream, CM_F32, Aq, Bk, sb, nullptr, nullptr,
                        SQ_, (long long)H_ * SQ_ * SQ_, (long long)SQ_ * SQ_,
                        SQ_, SQ_, HD_, B_ * H_, H_, iscale, nullptr);
            }
            k_softmax<<<B_ * H_ * SQ_, 256, 0, stream>>>(sb, ph, pl, SQ_, 0);
            {
                BfMat Ap = {ph, pl, SQ_, (long long)H_ * SQ_ * SQ_, (long long)SQ_ * SQ_};
                BfMat Bv = {vth, vtl, B_ * SQ_, SQ_, (long long)HD_ * B_ * SQ_};
                gemm_bf(stream, CM_PAIR, Ap, Bv, nullptr, ctxh, ctxl,
                        D_, (long long)SQ_ * D_, HD_,
                        SQ_, HD_, SQ_, B_ * H_, H_, 1.f, nullptr);
            }
            split_w(stream, wo + woff, wsh, wsl, 1048576);
            {
                BfMat Actx = {ctxh, ctxl, D_, 0, 0};
                gemm_bf(stream, CM_F32, Actx, Wscr, ob, nullptr, nullptr, D_, 0, 0,
                        B_ * SQ_, D_, D_, 1, 1, 1.f, nullptr);
            }
            k_add<<<2048, 256, 0, stream>>>(xb, ob);

            k_rmsnorm<<<B_ * SQ_, 256, 0, stream>>>(xb, n2w + l * D_, nullptr, hbh, hbl);
            split_w(stream, wg + foff, wsh, wsl, 4194304);
            gemm_bf(stream, CM_F32, Ahb, Wscr, ffg, nullptr, nullptr, FF_, 0, 0,
                    B_ * SQ_, FF_, D_, 1, 1, 1.f, nullptr);
            split_w(stream, wu + foff, wsh, wsl, 4194304);
            gemm_bf(stream, CM_F32, Ahb, Wscr, ffu, nullptr, nullptr, FF_, 0, 0,
                    B_ * SQ_, FF_, D_, 1, 1, 1.f, nullptr);
            k_silu_mul<<<32768, 256, 0, stream>>>(ffg, ffu, ffh, ffl);
            split_w(stream, wdn + foff, wsh, wsl, 4194304);
            {
                BfMat Aff = {ffh, ffl, FF_, 0, 0};
                BfMat Wd  = {wsh, wsl, FF_, 0, 0};
                gemm_bf(stream, CM_F32, Aff, Wd, ob, nullptr, nullptr, D_, 0, 0,
                        B_ * SQ_, D_, FF_, 1, 1, 1.f, nullptr);
            }
            k_add<<<2048, 256, 0, stream>>>(xb, ob);
        }

        // --- final ---
        k_rmsnorm<<<B_ * SQ_, 256, 0, stream>>>(xb, gnw, qb, hbh, hbl);
        {
            int chunks[4] = {8192, 8192, 8192, 7424};
            int coff = 0;
            for (int c = 0; c < 4; ++c) {
                split_w(stream, lmw + (size_t)coff * D_, wsh, wsl, (long long)chunks[c] * D_);
                gemm_bf(stream, CM_F32, Ahb, Wscr, logits + coff, nullptr, nullptr,
                        VOCAB_, 0, 0, B_ * SQ_, chunks[c], D_, 1, 1, 1.f, nullptr);
                coff += chunks[c];
            }
        }
        k_meanpool<<<8, 256, 0, stream>>>(qb, pooled);
        gemm(stream, pooled, D_, 0, mw1, D_, 0, mbuf, 256, 0,
             1, B_, 256, D_, 1.f, mb1, false);
        k_gelu<<<2, 256, 0, stream>>>(mbuf, B_ * 256);
        gemm(stream, mbuf, 256, 0, mw2, 256, 0, meta, 3, 0,
             1, B_, 3, 256, 1.f, mb2, false);
        return;
    }

    // =================== fp32 fallback path (round-1, verified) ===================
    float* ws    = (float*)d_ws;
    float* allkv = ws;
    float* xb    = allkv + 4194304;
    float* hb    = xb + 2097152;
    float* qb    = hb + 2097152;
    float* ctx   = qb + 2097152;
    float* ob    = ctx + 2097152;
    float* kb    = ob + 2097152;
    float* vb    = kb + 4194304;
    float* sb    = vb + 4194304;
    float* ffg   = sb;
    float* ffu   = sb + 8388608;
    float* sml2  = sb + 16777216;
    float* summ  = sml2;
    float* agh   = summ + 8192;
    float* ago   = agh + 4096;
    float* agr   = ago + 2048;
    float* pooled= agr + 2048;
    float* mbuf  = pooled + 2048;
    if (ws_size < (size_t)39911424 * 4) return;

    k_weighted_kv<<<4096, 256, 0, stream>>>(rh, conf, allkv, nullptr, nullptr);
    k_summaries<<<32, 256, 0, stream>>>(rh, summ);
    hipMemcpyAsync(xb, qh, (size_t)2097152 * 4, hipMemcpyDeviceToDevice, stream);

    for (int i = 0; i < 2; ++i) {
        const float* inw = cainw + (size_t)i * 3 * D_ * D_;
        const float* inb = cainb + (size_t)i * 3 * D_;
        k_rmsnorm<<<B_ * SQ_, 256, 0, stream>>>(xb, cnorm + i * D_, hb, nullptr, nullptr);
        gemm(stream, hb, D_, 0, inw, D_, 0, qb, D_, 0, 1, B_ * SQ_, D_, D_, 1.f, inb, false);
        gemm(stream, allkv, D_, 0, inw + 1048576, D_, 0, kb, D_, 0, 1, B_ * SKVT_, D_, D_, 1.f, inb + D_, false);
        gemm(stream, allkv, D_, 0, inw + 2097152, D_, 0, vb, D_, 0, 1, B_ * SKVT_, D_, D_, 1.f, inb + 2 * D_, false);
        for (int b = 0; b < B_; ++b) {
            gemm(stream, qb + (size_t)b * SQ_ * D_, D_, HD_,
                 kb + (size_t)b * SKVT_ * D_, D_, HD_,
                 sb, SKVT_, (long long)SQ_ * SKVT_,
                 H_, SQ_, SKVT_, HD_, iscale, nullptr, false);
            k_softmax<<<H_ * SQ_, 256, 0, stream>>>(sb, nullptr, nullptr, SKVT_, 1);
            if (i == 1)
                k_attn_mean<<<8192, 256, 0, stream>>>(sb, attnw + (size_t)b * SQ_ * SKVT_);
            gemm(stream, sb, SKVT_, (long long)SQ_ * SKVT_,
                 vb + (size_t)b * SKVT_ * D_, D_, HD_,
                 ctx + (size_t)b * SQ_ * D_, D_, HD_,
                 H_, SQ_, HD_, SKVT_, 1.f, nullptr, true);
        }
        gemm(stream, ctx, D_, 0, caoutw + (size_t)i * D_ * D_, D_, 0, ob, D_, 0,
             1, B_ * SQ_, D_, D_, 1.f, caoutb + i * D_, false);
        k_add<<<2048, 256, 0, stream>>>(xb, ob);
    }

    gemm(stream, summ, NR_ * D_, 0, agw1, NR_ * D_, 0, agh, 2 * D_, 0,
         1, B_, 2 * D_, NR_ * D_, 1.f, agb1, false);
    k_gelu<<<16, 256, 0, stream>>>(agh, B_ * 2 * D_);
    gemm(stream, agh, 2 * D_, 0, agw2, 2 * D_, 0, ago, D_, 0,
         1, B_, D_, 2 * D_, 1.f, agb2, false);
    k_rmsnorm<<<B_, 256, 0, stream>>>(ago, agnw, agr, nullptr, nullptr);
    k_add_bcast<<<8192, 256, 0, stream>>>(xb, agr);

    for (int l = 0; l < NL_; ++l) {
        const size_t woff = (size_t)l * D_ * D_;
        const size_t foff = (size_t)l * FF_ * D_;
        k_rmsnorm<<<B_ * SQ_, 256, 0, stream>>>(xb, n1w + l * D_, hb, nullptr, nullptr);
        gemm(stream, hb, D_, 0, wq + woff, D_, 0, qb, D_, 0, 1, B_ * SQ_, D_, D_, 1.f, nullptr, false);
        gemm(stream, hb, D_, 0, wk + woff, D_, 0, kb, D_, 0, 1, B_ * SQ_, D_, D_, 1.f, nullptr, false);
        gemm(stream, hb, D_, 0, wv + woff, D_, 0, vb, D_, 0, 1, B_ * SQ_, D_, D_, 1.f, nullptr, false);
        k_rope<<<4096, 256, 0, stream>>>(qb, kb, nullptr, nullptr, nullptr, nullptr);
        for (int b = 0; b < B_; ++b) {
            gemm(stream, qb + (size_t)b * SQ_ * D_, D_, HD_,
                 kb + (size_t)b * SQ_ * D_, D_, HD_,
                 sb, SQ_, (long long)SQ_ * SQ_,
                 H_, SQ_, SQ_, HD_, iscale, nullptr, false);
            k_softmax<<<H_ * SQ_, 256, 0, stream>>>(sb, nullptr, nullptr, SQ_, 1);
            gemm(stream, sb, SQ_, (long long)SQ_ * SQ_,
                 vb + (size_t)b * SQ_ * D_, D_, HD_,
                 ctx + (size_t)b * SQ_ * D_, D_, HD_,
                 H_, SQ_, HD_, SQ_, 1.f, nullptr, true);
        }
        gemm(stream, ctx, D_, 0, wo + woff, D_, 0, ob, D_, 0, 1, B_ * SQ_, D_, D_, 1.f, nullptr, false);
        k_add<<<2048, 256, 0, stream>>>(xb, ob);

        k_rmsnorm<<<B_ * SQ_, 256, 0, stream>>>(xb, n2w + l * D_, hb, nullptr, nullptr);
        gemm(stream, hb, D_, 0, wg + foff, D_, 0, ffg, FF_, 0, 1, B_ * SQ_, FF_, D_, 1.f, nullptr, false);
        gemm(stream, hb, D_, 0, wu + foff, D_, 0, ffu, FF_, 0, 1, B_ * SQ_, FF_, D_, 1.f, nullptr, false);
        k_silu_mul<<<32768, 256, 0, stream>>>(ffg, ffu, nullptr, nullptr);
        gemm(stream, ffg, FF_, 0, wdn + foff, FF_, 0, ob, D_, 0, 1, B_ * SQ_, D_, FF_, 1.f, nullptr, false);
        k_add<<<2048, 256, 0, stream>>>(xb, ob);
    }

    k_rmsnorm<<<B_ * SQ_, 256, 0, stream>>>(xb, gnw, hb, nullptr, nullptr);
    gemm(stream, hb, D_, 0, lmw, D_, 0, logits, VOCAB_, 0,
         1, B_ * SQ_, VOCAB_, D_, 1.f, nullptr, false);
    k_meanpool<<<8, 256, 0, stream>>>(hb, pooled);
    gemm(stream, pooled, D_, 0, mw1, D_, 0, mbuf, 256, 0,
         1, B_, 256, D_, 1.f, mb1, false);
    k_gelu<<<2, 256, 0, stream>>>(mbuf, B_ * 256);
    gemm(stream, mbuf, 256, 0, mw2, 256, 0, meta, 3, 0,
         1, B_, 3, 256, 1.f, mb2, false);
}

// Round 3
// 7400.220 us; speedup vs baseline: 2.7835x; 1.1345x over previous
//
#include <hip/hip_runtime.h>
#include <math.h>

// Model dims (fixed by the reference)
#define D_     1024
#define H_     8
#define HD_    128
#define NR_    4
#define B_     2
#define SQ_    1024
#define SKV_   512
#define SKVT_  2048
#define VOCAB_ 32000
#define NL_    6
#define FF_    4096
#define EPS_   1e-6f

typedef unsigned short u16;
typedef __attribute__((ext_vector_type(8))) __bf16 bf16x8;
typedef __attribute__((ext_vector_type(4))) float f32x4;

// ---------------- bf16 split helpers (RNE) ----------------
__device__ __forceinline__ u16 f2bf_rn(float f) {
    unsigned u = __float_as_uint(f);
    unsigned r = (u + 0x7FFFu + ((u >> 16) & 1u)) >> 16;
    return (u16)r;
}
__device__ __forceinline__ float bf2f(u16 h) {
    return __uint_as_float(((unsigned)h) << 16);
}
__device__ __forceinline__ void splitf(float v, u16& h, u16& l) {
    h = f2bf_rn(v);
    l = f2bf_rn(v - bf2f(h));
}

// async global->LDS, 16B per lane, wave-uniform LDS base
__device__ __forceinline__ void glds16(const u16* g, const u16* l) {
    __builtin_amdgcn_global_load_lds(
        (const __attribute__((address_space(1))) void*)g,
        (__attribute__((address_space(3))) void*)l,
        16, 0, 0);
}

// ===========================================================================
// MFMA split-bf16 GEMM (m97 structure). 3 passes: Ah*Bh + Al*Bh + Ah*Bl.
//   C[z] = scale * A[z] @ B[z]^T + bias (+resid, CM_F32 only)
//   M%128==0, N%128==0, K%32==0. z = zb*ZH+zh with separate strides.
// ===========================================================================
enum { CM_F32 = 0, CM_PAIR = 1, CM_PAIRT = 2 };

template<int CMODE>
__global__ __launch_bounds__(256, 3)
void k_gemm_bf(const u16* __restrict__ Ah, const u16* __restrict__ Al,
               int lda, long long sAb, long long sAh,
               const u16* __restrict__ Bh, const u16* __restrict__ Bl,
               int ldb, long long sBb, long long sBh,
               float* __restrict__ Cf, u16* __restrict__ Ch, u16* __restrict__ Cl,
               int ldc, long long sCb, long long sCh,
               int K, int ZH, float scale, const float* __restrict__ bias,
               const float* __restrict__ resid)
{
    // 4 tiles (Ah, Al, Bh, Bl), each [4 slabs][128 rows][8 bf16 = 16B] = 8KB
    __shared__ u16 lds[16384];

    const int z  = blockIdx.z;
    const int zb = z / ZH, zh = z - zb * ZH;
    const long long offA = zb * sAb + zh * sAh;
    const long long offB = zb * sBb + zh * sBh;
    const long long offC = zb * sCb + zh * sCh;

    const int m0 = blockIdx.y << 7, n0 = blockIdx.x << 7;
    const int tid = threadIdx.x, lane = tid & 63, w = tid >> 6;
    const int wr = w >> 1, wc = w & 1;

    const u16* pAh = Ah + offA; const u16* pAl = Al + offA;
    const u16* pBh = Bh + offB; const u16* pBl = Bl + offB;

    f32x4 acc[4][4];
#pragma unroll
    for (int i = 0; i < 4; ++i)
#pragma unroll
        for (int j = 0; j < 4; ++j) acc[i][j] = (f32x4){0.f, 0.f, 0.f, 0.f};

    const int ks = lane >> 4, lr16 = lane & 15;

    for (int k0 = 0; k0 < K; k0 += 32) {
        // ---- stage: 8 chunks of 1KB per tile; chunk = slab*2+half ----
#pragma unroll
        for (int c = 0; c < 2; ++c) {
            const int chunk = w * 2 + c;
            const int slab = chunk >> 1, hf = chunk & 1;
            const int row = hf * 64 + lane;
            const int lbase = (slab * 128 + hf * 64) * 8;   // u16 index, wave-uniform
            const long long ga = (long long)(m0 + row) * lda + (k0 + slab * 8);
            const long long gb = (long long)(n0 + row) * ldb + (k0 + slab * 8);
            glds16(pAh + ga, &lds[lbase]);
            glds16(pAl + ga, &lds[4096 + lbase]);
            glds16(pBh + gb, &lds[8192 + lbase]);
            glds16(pBl + gb, &lds[12288 + lbase]);
        }
        __syncthreads();

        // ---- fragments + MFMA ----
        bf16x8 bh[4], bl[4];
#pragma unroll
        for (int nj = 0; nj < 4; ++nj) {
            const int off = (ks * 128 + wc * 64 + nj * 16 + lr16) * 8;
            bh[nj] = *(const bf16x8*)&lds[8192 + off];
            bl[nj] = *(const bf16x8*)&lds[12288 + off];
        }
#pragma unroll
        for (int mi = 0; mi < 4; ++mi) {
            const int off = (ks * 128 + wr * 64 + mi * 16 + lr16) * 8;
            bf16x8 ah = *(const bf16x8*)&lds[off];
            bf16x8 al = *(const bf16x8*)&lds[4096 + off];
#pragma unroll
            for (int nj = 0; nj < 4; ++nj) {
                acc[mi][nj] = __builtin_amdgcn_mfma_f32_16x16x32_bf16(ah, bh[nj], acc[mi][nj], 0, 0, 0);
                acc[mi][nj] = __builtin_amdgcn_mfma_f32_16x16x32_bf16(al, bh[nj], acc[mi][nj], 0, 0, 0);
                acc[mi][nj] = __builtin_amdgcn_mfma_f32_16x16x32_bf16(ah, bl[nj], acc[mi][nj], 0, 0, 0);
            }
        }
        __syncthreads();
    }

    // ---- epilogue: C[row=m][col=n], m = wr*64+mi*16+(lane>>4)*4+j, n = wc*64+nj*16+(lane&15)
#pragma unroll
    for (int mi = 0; mi < 4; ++mi) {
#pragma unroll
        for (int nj = 0; nj < 4; ++nj) {
#pragma unroll
            for (int j = 0; j < 4; ++j) {
                const int row = m0 + wr * 64 + mi * 16 + (lane >> 4) * 4 + j;
                const int col = n0 + wc * 64 + nj * 16 + lr16;
                float v = acc[mi][nj][j] * scale;
                if (bias) v += bias[col];
                if (CMODE == CM_F32) {
                    const long long idx = offC + (long long)row * ldc + col;
                    if (resid) v += resid[idx];
                    Cf[idx] = v;
                } else {
                    u16 h, l;
                    splitf(v, h, l);
                    const long long idx = (CMODE == CM_PAIR)
                        ? offC + (long long)row * ldc + col
                        : offC + (long long)col * ldc + row;
                    Ch[idx] = h; Cl[idx] = l;
                }
            }
        }
    }
}

// ---------------------------------------------------------------------------
// Skinny GEMM for tiny M (agreement/meta): one wave per output element.
//   C[m][n] = gelu?( sum_k A[m][k]*B[n][k] + bias[n] )   K % 256 == 0
// ---------------------------------------------------------------------------
__global__ __launch_bounds__(256)
void k_skinny(const float* __restrict__ A, int lda,
              const float* __restrict__ B, int ldb,
              const float* __restrict__ bias,
              float* __restrict__ C, int ldc,
              int M, int N, int K, int gelu)
{
    int w = (blockIdx.x * 256 + threadIdx.x) >> 6;
    int lane = threadIdx.x & 63;
    if (w >= M * N) return;
    int m = w / N, n = w - m * N;
    const float* a = A + (long long)m * lda;
    const float* b = B + (long long)n * ldb;
    float s = 0.f;
    for (int k = lane * 4; k < K; k += 256) {
        float4 av = *(const float4*)(a + k);
        float4 bv = *(const float4*)(b + k);
        s += av.x * bv.x + av.y * bv.y + av.z * bv.z + av.w * bv.w;
    }
#pragma unroll
    for (int off = 32; off >= 1; off >>= 1) s += __shfl_xor(s, off);
    if (lane == 0) {
        if (bias) s += bias[n];
        if (gelu) s = 0.5f * s * (1.0f + erff(s * 0.7071067811865476f));
        C[(long long)m * ldc + n] = s;
    }
}

// ---------------------------------------------------------------------------
// fp32 fallback GEMM (round-1 kernel, unchanged; used only on fallback path)
// ---------------------------------------------------------------------------
template<bool BTRANS>
__global__ __launch_bounds__(256)
void k_gemm(const float* __restrict__ A, int lda, long long sA,
            const float* __restrict__ B, int ldb, long long sB,
            float* __restrict__ C, int ldc, long long sC,
            int M, int N, int K, float scale, const float* __restrict__ bias)
{
    __shared__ float As[16][128];
    __shared__ float Bs[16][128];

    const int z = blockIdx.z;
    A += (long long)z * sA;
    B += (long long)z * sB;
    C += (long long)z * sC;

    const int m0 = blockIdx.y * 128;
    const int n0 = blockIdx.x * 128;
    const int tid = threadIdx.x;
    const int tm = tid >> 4;
    const int tn = tid & 15;
    const int lr = tid >> 2;
    const int lc = (tid & 3) << 2;

    float acc[8][8];
#pragma unroll
    for (int i = 0; i < 8; ++i)
#pragma unroll
        for (int j = 0; j < 8; ++j) acc[i][j] = 0.f;

    for (int k0 = 0; k0 < K; k0 += 16) {
#pragma unroll
        for (int r = 0; r < 2; ++r) {
            int m = lr + r * 64;
            float4 av = make_float4(0.f, 0.f, 0.f, 0.f);
            if (m0 + m < M)
                av = *(const float4*)(A + (long long)(m0 + m) * lda + (k0 + lc));
            As[lc + 0][m] = av.x; As[lc + 1][m] = av.y;
            As[lc + 2][m] = av.z; As[lc + 3][m] = av.w;
        }
        if (!BTRANS) {
#pragma unroll
            for (int r = 0; r < 2; ++r) {
                int n = lr + r * 64;
                float4 bv = make_float4(0.f, 0.f, 0.f, 0.f);
                if (n0 + n < N)
                    bv = *(const float4*)(B + (long long)(n0 + n) * ldb + (k0 + lc));
                Bs[lc + 0][n] = bv.x; Bs[lc + 1][n] = bv.y;
                Bs[lc + 2][n] = bv.z; Bs[lc + 3][n] = bv.w;
            }
        } else {
            int kk = tid >> 5;
            int nn = (tid & 31) << 2;
#pragma unroll
            for (int r = 0; r < 2; ++r) {
                int k = kk + r * 8;
                float4 bv = make_float4(0.f, 0.f, 0.f, 0.f);
                if (n0 + nn < N)
                    bv = *(const float4*)(B + (long long)(k0 + k) * ldb + (n0 + nn));
                *(float4*)&Bs[k][nn] = bv;
            }
        }
        __syncthreads();

#pragma unroll
        for (int kk = 0; kk < 16; ++kk) {
            float a[8], b[8];
            *(float4*)&a[0] = *(const float4*)&As[kk][tm * 8];
            *(float4*)&a[4] = *(const float4*)&As[kk][tm * 8 + 4];
            *(float4*)&b[0] = *(const float4*)&Bs[kk][tn * 8];
            *(float4*)&b[4] = *(const float4*)&Bs[kk][tn * 8 + 4];
#pragma unroll
            for (int i = 0; i < 8; ++i)
#pragma unroll
                for (int j = 0; j < 8; ++j)
                    acc[i][j] = fmaf(a[i], b[j], acc[i][j]);
        }
        __syncthreads();
    }

#pragma unroll
    for (int i = 0; i < 8; ++i) {
        int m = m0 + tm * 8 + i;
        if (m < M) {
#pragma unroll
            for (int j = 0; j < 8; ++j) {
                int n = n0 + tn * 8 + j;
                if (n < N) {
                    float v = acc[i][j] * scale;
                    if (bias) v += bias[n];
                    C[(long long)m * ldc + n] = v;
                }
            }
        }
    }
}

// ---------------------------------------------------------------------------
// RMSNorm, rows of 1024. Writes fp32 (if yf) and/or bf16 pair (if yh).
// ---------------------------------------------------------------------------
__global__ __launch_bounds__(256)
void k_rmsnorm(const float* __restrict__ x, const float* __restrict__ w,
               float* __restrict__ yf, u16* __restrict__ yh, u16* __restrict__ yl)
{
    long long row = blockIdx.x;
    const float* xr = x + row * D_;
    int tid = threadIdx.x;

    float4 v = *(const float4*)(xr + tid * 4);
    float ss = v.x * v.x + v.y * v.y + v.z * v.z + v.w * v.w;
#pragma unroll
    for (int off = 32; off >= 1; off >>= 1) ss += __shfl_xor(ss, off);
    __shared__ float red[4];
    if ((tid & 63) == 0) red[tid >> 6] = ss;
    __syncthreads();
    float tot = red[0] + red[1] + red[2] + red[3];
    float sc = 1.0f / sqrtf(tot * (1.0f / D_) + EPS_);

    float4 wv = *(const float4*)(w + tid * 4);
    float o[4];
    o[0] = v.x * sc * wv.x; o[1] = v.y * sc * wv.y;
    o[2] = v.z * sc * wv.z; o[3] = v.w * sc * wv.w;
    if (yf) *(float4*)(yf + row * D_ + tid * 4) = make_float4(o[0], o[1], o[2], o[3]);
    if (yh) {
        u16 h[4], l[4];
#pragma unroll
        for (int i = 0; i < 4; ++i) splitf(o[i], h[i], l[i]);
        uint2 ph = make_uint2((unsigned)h[0] | ((unsigned)h[1] << 16),
                              (unsigned)h[2] | ((unsigned)h[3] << 16));
        uint2 pl = make_uint2((unsigned)l[0] | ((unsigned)l[1] << 16),
                              (unsigned)l[2] | ((unsigned)l[3] << 16));
        ((uint2*)(yh + row * D_))[tid] = ph;
        ((uint2*)(yl + row * D_))[tid] = pl;
    }
}

// ---------------------------------------------------------------------------
// Row softmax: fp32 in-place (if wf32), bf16 pair out (if Ph).
// ---------------------------------------------------------------------------
__global__ __launch_bounds__(256)
void k_softmax(float* __restrict__ S, u16* __restrict__ Ph, u16* __restrict__ Pl,
               int N, int wf32)
{
    __shared__ float buf[2048];
    __shared__ float red[4];
    long long row = blockIdx.x;
    float* p = S + row * (long long)N;
    int tid = threadIdx.x;

    float mx = -1e30f;
    for (int i = tid; i < N; i += 256) { float v = p[i]; buf[i] = v; mx = fmaxf(mx, v); }
#pragma unroll
    for (int off = 32; off >= 1; off >>= 1) mx = fmaxf(mx, __shfl_xor(mx, off));
    if ((tid & 63) == 0) red[tid >> 6] = mx;
    __syncthreads();
    mx = fmaxf(fmaxf(red[0], red[1]), fmaxf(red[2], red[3]));

    float sum = 0.f;
    for (int i = tid; i < N; i += 256) { float e = __expf(buf[i] - mx); buf[i] = e; sum += e; }
#pragma unroll
    for (int off = 32; off >= 1; off >>= 1) sum += __shfl_xor(sum, off);
    __syncthreads();
    if ((tid & 63) == 0) red[tid >> 6] = sum;
    __syncthreads();
    sum = red[0] + red[1] + red[2] + red[3];
    float inv = 1.0f / sum;
    for (int i = tid; i < N; i += 256) {
        float pv = buf[i] * inv;
        if (wf32) p[i] = pv;
        if (Ph) {
            u16 h, l;
            splitf(pv, h, l);
            Ph[row * (long long)N + i] = h;
            Pl[row * (long long)N + i] = l;
        }
    }
}

// ---------------------------------------------------------------------------
// weighted KV: fp32 out (old path) or bf16 pair (mfma path). 4 elems/thread.
// ---------------------------------------------------------------------------
__global__ void k_weighted_kv(const float* __restrict__ rh,
                              const float* __restrict__ conf,
                              float* __restrict__ kvf,
                              u16* __restrict__ kvh, u16* __restrict__ kvl)
{
    int i4 = blockIdx.x * 256 + threadIdx.x;       // total (B*NR*SKV*D)/4 = 2^20
    int d4 = i4 & 255;
    int s  = (i4 >> 8) & (SKV_ - 1);
    int n  = (i4 >> 17) & (NR_ - 1);
    int b  = i4 >> 19;
    float c = conf[b * NR_ + n];
    float4 v = ((const float4*)(rh + (((long long)(n * B_ + b) * SKV_ + s) * D_)))[d4];
    v.x *= c; v.y *= c; v.z *= c; v.w *= c;
    if (kvf) ((float4*)kvf)[i4] = v;
    if (kvh) {
        u16 h[4], l[4];
        splitf(v.x, h[0], l[0]); splitf(v.y, h[1], l[1]);
        splitf(v.z, h[2], l[2]); splitf(v.w, h[3], l[3]);
        ((uint2*)kvh)[i4] = make_uint2((unsigned)h[0] | ((unsigned)h[1] << 16),
                                       (unsigned)h[2] | ((unsigned)h[3] << 16));
        ((uint2*)kvl)[i4] = make_uint2((unsigned)l[0] | ((unsigned)l[1] << 16),
                                       (unsigned)l[2] | ((unsigned)l[3] << 16));
    }
}

// summaries[b, n*D+d] = mean_s rh[n,b,s,d]
__global__ void k_summaries(const float* __restrict__ rh, float* __restrict__ sm)
{
    int idx = blockIdx.x * 256 + threadIdx.x;      // B*NR*D = 8192
    int d = idx & (D_ - 1);
    int n = (idx >> 10) & (NR_ - 1);
    int b = idx >> 12;
    const float* p = rh + ((long long)(n * B_ + b) * SKV_) * D_ + d;
    float s = 0.f;
    for (int t = 0; t < SKV_; ++t) s += p[(long long)t * D_];
    sm[idx] = s * (1.0f / SKV_);
}

// out[m,n] = mean_h S[h,m,n]
__global__ void k_attn_mean(const float* __restrict__ S, float* __restrict__ O)
{
    int idx = blockIdx.x * 256 + threadIdx.x;      // SQ*SKVT = 2^21
    float s = 0.f;
#pragma unroll
    for (int h = 0; h < H_; ++h) s += S[(long long)h * SQ_ * SKVT_ + idx];
    O[idx] = s * (1.0f / H_);
}

// RoPE: fp32 in-place (old path, qh==null) OR write bf16 pairs (mfma path)
__global__ void k_rope(float* __restrict__ q, float* __restrict__ k,
                       u16* __restrict__ qh, u16* __restrict__ ql,
                       u16* __restrict__ kh, u16* __restrict__ kl)
{
    int idx = blockIdx.x * 256 + threadIdx.x;      // B*SQ*H*64 = 2^20
    int j = idx & 63;
    int h = (idx >> 6) & (H_ - 1);
    int s = (idx >> 9) & (SQ_ - 1);
    int b = idx >> 19;
    float inv = __expf(-9.210340371976184f * (float)j * (1.0f / 64.0f));
    float ang = (float)s * inv;
    float sn, cs;
    __sincosf(ang, &sn, &cs);
    long long base = ((long long)(b * SQ_ + s)) * D_ + h * HD_ + j;
    float q1 = q[base], q2 = q[base + 64];
    float qo1 = q1 * cs - q2 * sn;
    float qo2 = q2 * cs + q1 * sn;
    float k1 = k[base], k2 = k[base + 64];
    float ko1 = k1 * cs - k2 * sn;
    float ko2 = k2 * cs + k1 * sn;
    if (qh) {
        u16 h0, l0;
        splitf(qo1, h0, l0); qh[base] = h0;      ql[base] = l0;
        splitf(qo2, h0, l0); qh[base + 64] = h0; ql[base + 64] = l0;
        splitf(ko1, h0, l0); kh[base] = h0;      kl[base] = l0;
        splitf(ko2, h0, l0); kh[base + 64] = h0; kl[base + 64] = l0;
    } else {
        q[base] = qo1; q[base + 64] = qo2;
        k[base] = ko1; k[base + 64] = ko2;
    }
}

// y += a (fallback path only)
__global__ void k_add(float* __restrict__ y, const float* __restrict__ a)
{
    int i = blockIdx.x * 256 + threadIdx.x;
    float4 v = *(const float4*)(y + i * 4);
    float4 u = *(const float4*)(a + i * 4);
    v.x += u.x; v.y += u.y; v.z += u.z; v.w += u.w;
    *(float4*)(y + i * 4) = v;
}

// x[b,s,:] += ag[b,:]
__global__ void k_add_bcast(float* __restrict__ x, const float* __restrict__ ag)
{
    int idx = blockIdx.x * 256 + threadIdx.x;
    int d = idx & (D_ - 1);
    int b = idx >> 20;
    x[idx] += ag[b * D_ + d];
}

__global__ void k_gelu(float* __restrict__ v, int n)
{
    int i = blockIdx.x * 256 + threadIdx.x;
    if (i < n) {
        float x = v[i];
        v[i] = 0.5f * x * (1.0f + erff(x * 0.7071067811865476f));
    }
}

// silu(g)*u -> fp32 in place (old) or bf16 pair (mfma)
__global__ void k_silu_mul(float* __restrict__ g, const float* __restrict__ u,
                           u16* __restrict__ fh, u16* __restrict__ fl)
{
    int i = blockIdx.x * 256 + threadIdx.x;
    float x = g[i];
    float r = (x / (1.0f + __expf(-x))) * u[i];
    if (fh) {
        u16 h, l;
        splitf(r, h, l);
        fh[i] = h; fl[i] = l;
    } else {
        g[i] = r;
    }
}

// fallback-path meanpool
__global__ void k_meanpool(const float* __restrict__ h, float* __restrict__ p)
{
    int idx = blockIdx.x * 256 + threadIdx.x;
    int d = idx & (D_ - 1);
    int b = idx >> 10;
    const float* r = h + ((long long)b * SQ_) * D_ + d;
    float s = 0.f;
    for (int t = 0; t < SQ_; ++t) s += r[(long long)t * D_];
    p[idx] = s * (1.0f / SQ_);
}

// two-stage meanpool: p1 sums 64-row chunks, p2 reduces 16 partials
__global__ void k_meanpool_p1(const float* __restrict__ h, float* __restrict__ part)
{
    int b = blockIdx.x >> 4, sc = blockIdx.x & 15;
    int t = threadIdx.x;                              // float4 idx 0..255
    const float* base = h + ((long long)b * SQ_ + sc * 64) * D_;
    float4 s = make_float4(0.f, 0.f, 0.f, 0.f);
    for (int r = 0; r < 64; ++r) {
        float4 v = ((const float4*)(base + (long long)r * D_))[t];
        s.x += v.x; s.y += v.y; s.z += v.z; s.w += v.w;
    }
    ((float4*)(part + (long long)(b * 16 + sc) * D_))[t] = s;
}
__global__ void k_meanpool_p2(const float* __restrict__ part, float* __restrict__ p)
{
    int idx = blockIdx.x * 256 + threadIdx.x;         // B*D = 2048
    int b = idx >> 10, d = idx & 1023;
    float s = 0.f;
#pragma unroll
    for (int c = 0; c < 16; ++c) s += part[(long long)(b * 16 + c) * D_ + d];
    p[idx] = s * (1.0f / SQ_);
}

// fp32 -> bf16 hi/lo split, 4 elems/thread
__global__ void k_split(const float* __restrict__ x, u16* __restrict__ h,
                        u16* __restrict__ l, int n4)
{
    int i = blockIdx.x * 256 + threadIdx.x;
    if (i < n4) {
        float4 v = ((const float4*)x)[i];
        u16 hh[4], ll[4];
        splitf(v.x, hh[0], ll[0]); splitf(v.y, hh[1], ll[1]);
        splitf(v.z, hh[2], ll[2]); splitf(v.w, hh[3], ll[3]);
        ((uint2*)h)[i] = make_uint2((unsigned)hh[0] | ((unsigned)hh[1] << 16),
                                    (unsigned)hh[2] | ((unsigned)hh[3] << 16));
        ((uint2*)l)[i] = make_uint2((unsigned)ll[0] | ((unsigned)ll[1] << 16),
                                    (unsigned)ll[2] | ((unsigned)ll[3] << 16));
    }
}

// ---------------------------------------------------------------------------
// host helpers
// ---------------------------------------------------------------------------
static void gemm(hipStream_t st,
                 const float* A, int lda, long long sA,
                 const float* B, int ldb, long long sB,
                 float* C, int ldc, long long sC,
                 int Z, int M, int N, int K, float scale, const float* bias,
                 bool btrans)
{
    dim3 g((N + 127) / 128, (M + 127) / 128, Z);
    if (btrans)
        k_gemm<true><<<g, 256, 0, st>>>(A, lda, sA, B, ldb, sB, C, ldc, sC, M, N, K, scale, bias);
    else
        k_gemm<false><<<g, 256, 0, st>>>(A, lda, sA, B, ldb, sB, C, ldc, sC, M, N, K, scale, bias);
}

struct BfMat { const u16* h; const u16* l; int ld; long long sb, sh; };

static void gemm_bf(hipStream_t st, int cmode,
                    BfMat A, BfMat B,
                    float* Cf, u16* Ch, u16* Cl, int ldc, long long sCb, long long sCh,
                    int M, int N, int K, int Z, int ZH, float scale, const float* bias,
                    const float* resid)
{
    dim3 g(N / 128, M / 128, Z);
    if (cmode == CM_F32)
        k_gemm_bf<CM_F32><<<g, 256, 0, st>>>(A.h, A.l, A.ld, A.sb, A.sh,
                                             B.h, B.l, B.ld, B.sb, B.sh,
                                             Cf, Ch, Cl, ldc, sCb, sCh, K, ZH, scale, bias, resid);
    else if (cmode == CM_PAIR)
        k_gemm_bf<CM_PAIR><<<g, 256, 0, st>>>(A.h, A.l, A.ld, A.sb, A.sh,
                                              B.h, B.l, B.ld, B.sb, B.sh,
                                              Cf, Ch, Cl, ldc, sCb, sCh, K, ZH, scale, bias, nullptr);
    else
        k_gemm_bf<CM_PAIRT><<<g, 256, 0, st>>>(A.h, A.l, A.ld, A.sb, A.sh,
                                               B.h, B.l, B.ld, B.sb, B.sh,
                                               Cf, Ch, Cl, ldc, sCb, sCh, K, ZH, scale, bias, nullptr);
}

static void split_w(hipStream_t st, const float* w, u16* h, u16* l, long long n)
{
    int n4 = (int)(n >> 2);
    k_split<<<(n4 + 255) / 256, 256, 0, st>>>(w, h, l, n4);
}

static void skinny(hipStream_t st, const float* A, int lda, const float* B, int ldb,
                   const float* bias, float* C, int ldc, int M, int N, int K, int gelu)
{
    int blocks = (M * N * 64 + 255) / 256;
    k_skinny<<<blocks, 256, 0, st>>>(A, lda, B, ldb, bias, C, ldc, M, N, K, gelu);
}

// ===========================================================================
extern "C" void kernel_launch(void* const* d_in, const int* in_sizes, int n_in,
                              void* d_out, int out_size, void* d_ws, size_t ws_size,
                              hipStream_t stream)
{
    const float* rh     = (const float*)d_in[0];
    const float* conf   = (const float*)d_in[1];
    const float* qh     = (const float*)d_in[3];
    const float* cainw  = (const float*)d_in[4];
    const float* cainb  = (const float*)d_in[5];
    const float* caoutw = (const float*)d_in[6];
    const float* caoutb = (const float*)d_in[7];
    const float* cnorm  = (const float*)d_in[8];
    const float* agw1   = (const float*)d_in[9];
    const float* agb1   = (const float*)d_in[10];
    const float* agw2   = (const float*)d_in[11];
    const float* agb2   = (const float*)d_in[12];
    const float* agnw   = (const float*)d_in[13];
    const float* n1w    = (const float*)d_in[14];
    const float* wq     = (const float*)d_in[15];
    const float* wk     = (const float*)d_in[16];
    const float* wv     = (const float*)d_in[17];
    const float* wo     = (const float*)d_in[18];
    const float* n2w    = (const float*)d_in[19];
    const float* wg     = (const float*)d_in[20];
    const float* wu     = (const float*)d_in[21];
    const float* wdn    = (const float*)d_in[22];
    const float* gnw    = (const float*)d_in[23];
    const float* lmw    = (const float*)d_in[24];
    const float* mw1    = (const float*)d_in[25];
    const float* mb1    = (const float*)d_in[26];
    const float* mw2    = (const float*)d_in[27];
    const float* mb2    = (const float*)d_in[28];

    float* out    = (float*)d_out;
    float* logits = out;
    float* meta   = out + 65536000;
    float* attnw  = out + 65536006;

    const float iscale = 0.08838834764831845f;   // 1/sqrt(128)
    const size_t MFMA_WS = 276905984ULL;

    if (ws_size >= MFMA_WS) {
        // =================== MFMA split-bf16 path ===================
        char* base = (char*)d_ws;
        float* xb    = (float*)(base + 0);            // 2,097,152 f
        float* qb    = (float*)(base + 8388608);
        float* kb    = (float*)(base + 16777216);
        float* ob    = (float*)(base + 25165824);     // free buffer: meanpool partials
        float* R1    = (float*)(base + 33554432);     // 16,777,216 f: sb | ffg+ffu
        float* sml   = (float*)(base + 100663296);    // small fp32
        u16* akvh = (u16*)(base + 100745216);
        u16* akvl = (u16*)(base + 109133824);
        u16* hbh  = (u16*)(base + 117522432);
        u16* hbl  = (u16*)(base + 121716736);
        u16* qph  = (u16*)(base + 125911040);
        u16* qpl  = (u16*)(base + 130105344);
        u16* kph  = (u16*)(base + 134299648);
        u16* kpl  = (u16*)(base + 142688256);
        u16* vth  = (u16*)(base + 151076864);
        u16* vtl  = (u16*)(base + 159465472);
        u16* ctxh = (u16*)(base + 167854080);
        u16* ctxl = (u16*)(base + 172048384);
        u16* R2h  = (u16*)(base + 176242688);
        u16* R2l  = (u16*)(base + 209797120);
        u16* wsh  = (u16*)(base + 243351552);
        u16* wsl  = (u16*)(base + 260128768);

        float* sb  = R1;
        float* ffg = R1;
        float* ffu = R1 + 8388608;
        u16* ph = R2h; u16* pl = R2l;
        u16* ffh = R2h; u16* ffl = R2l;

        float* summ   = sml;
        float* agh    = summ + 8192;
        float* ago    = agh + 4096;
        float* agr    = ago + 2048;
        float* pooled = agr + 2048;
        float* mbuf   = pooled + 2048;
        float* mpart  = ob;                           // meanpool partials [B*16][D]

        // --- stage 0 ---
        k_weighted_kv<<<4096, 256, 0, stream>>>(rh, conf, nullptr, akvh, akvl);
        k_summaries<<<32, 256, 0, stream>>>(rh, summ);
        hipMemcpyAsync(xb, qh, (size_t)2097152 * 4, hipMemcpyDeviceToDevice, stream);

        BfMat Ahb  = {hbh, hbl, D_, 0, 0};
        BfMat Akv  = {akvh, akvl, D_, 0, 0};
        BfMat Wscr = {wsh, wsl, D_, 0, 0};

        // --- cross-attention x2 ---
        for (int i = 0; i < 2; ++i) {
            const float* inw = cainw + (size_t)i * 3 * D_ * D_;
            const float* inb = cainb + (size_t)i * 3 * D_;
            k_rmsnorm<<<B_ * SQ_, 256, 0, stream>>>(xb, cnorm + i * D_, nullptr, hbh, hbl);
            // q
            split_w(stream, inw, wsh, wsl, 1048576);
            gemm_bf(stream, CM_PAIR, Ahb, Wscr, nullptr, qph, qpl, D_, 0, 0,
                    B_ * SQ_, D_, D_, 1, 1, 1.f, inb, nullptr);
            // k
            split_w(stream, inw + 1048576, wsh, wsl, 1048576);
            gemm_bf(stream, CM_PAIR, Akv, Wscr, nullptr, kph, kpl, D_, 0, 0,
                    B_ * SKVT_, D_, D_, 1, 1, 1.f, inb + D_, nullptr);
            // v -> transposed [D][B*SKVT]
            split_w(stream, inw + 2097152, wsh, wsl, 1048576);
            gemm_bf(stream, CM_PAIRT, Akv, Wscr, nullptr, vth, vtl, B_ * SKVT_, 0, 0,
                    B_ * SKVT_, D_, D_, 1, 1, 1.f, inb + 2 * D_, nullptr);

            for (int b = 0; b < B_; ++b) {
                BfMat Aq = {qph + (size_t)b * SQ_ * D_, qpl + (size_t)b * SQ_ * D_, D_, 0, HD_};
                BfMat Bk = {kph + (size_t)b * SKVT_ * D_, kpl + (size_t)b * SKVT_ * D_, D_, 0, HD_};
                gemm_bf(stream, CM_F32, Aq, Bk, sb, nullptr, nullptr,
                        SKVT_, 0, (long long)SQ_ * SKVT_,
                        SQ_, SKVT_, HD_, H_, H_, iscale, nullptr, nullptr);
                k_softmax<<<H_ * SQ_, 256, 0, stream>>>(sb, ph, pl, SKVT_, (i == 1) ? 1 : 0);
                if (i == 1)
                    k_attn_mean<<<8192, 256, 0, stream>>>(sb, attnw + (size_t)b * SQ_ * SKVT_);
                BfMat Ap = {ph, pl, SKVT_, 0, (long long)SQ_ * SKVT_};
                BfMat Bv = {vth + (size_t)b * SKVT_, vtl + (size_t)b * SKVT_,
                            B_ * SKVT_, 0, (long long)HD_ * B_ * SKVT_};
                gemm_bf(stream, CM_PAIR, Ap, Bv, nullptr,
                        ctxh + (size_t)b * SQ_ * D_, ctxl + (size_t)b * SQ_ * D_,
                        D_, 0, HD_, SQ_, HD_, SKVT_, H_, H_, 1.f, nullptr, nullptr);
            }
            // out proj, residual fused: xb = ctx @ Wout^T + b + xb
            split_w(stream, caoutw + (size_t)i * D_ * D_, wsh, wsl, 1048576);
            BfMat Actx = {ctxh, ctxl, D_, 0, 0};
            gemm_bf(stream, CM_F32, Actx, Wscr, xb, nullptr, nullptr, D_, 0, 0,
                    B_ * SQ_, D_, D_, 1, 1, 1.f, caoutb + i * D_, xb);
        }

        // --- agreement (skinny M=2 GEMMs, fused GELU) ---
        skinny(stream, summ, NR_ * D_, agw1, NR_ * D_, agb1, agh, 2 * D_,
               B_, 2 * D_, NR_ * D_, 1);
        skinny(stream, agh, 2 * D_, agw2, 2 * D_, agb2, ago, D_,
               B_, D_, 2 * D_, 0);
        k_rmsnorm<<<B_, 256, 0, stream>>>(ago, agnw, agr, nullptr, nullptr);
        k_add_bcast<<<8192, 256, 0, stream>>>(xb, agr);

        // --- generator layers x6 ---
        for (int l = 0; l < NL_; ++l) {
            const size_t woff = (size_t)l * D_ * D_;
            const size_t foff = (size_t)l * FF_ * D_;
            k_rmsnorm<<<B_ * SQ_, 256, 0, stream>>>(xb, n1w + l * D_, nullptr, hbh, hbl);
            split_w(stream, wq + woff, wsh, wsl, 1048576);
            gemm_bf(stream, CM_F32, Ahb, Wscr, qb, nullptr, nullptr, D_, 0, 0,
                    B_ * SQ_, D_, D_, 1, 1, 1.f, nullptr, nullptr);
            split_w(stream, wk + woff, wsh, wsl, 1048576);
            gemm_bf(stream, CM_F32, Ahb, Wscr, kb, nullptr, nullptr, D_, 0, 0,
                    B_ * SQ_, D_, D_, 1, 1, 1.f, nullptr, nullptr);
            split_w(stream, wv + woff, wsh, wsl, 1048576);
            gemm_bf(stream, CM_PAIRT, Ahb, Wscr, nullptr, vth, vtl, B_ * SQ_, 0, 0,
                    B_ * SQ_, D_, D_, 1, 1, 1.f, nullptr, nullptr);
            k_rope<<<4096, 256, 0, stream>>>(qb, kb, qph, qpl, kph, kpl);

            {
                BfMat Aq = {qph, qpl, D_, (long long)SQ_ * D_, HD_};
                BfMat Bk = {kph, kpl, D_, (long long)SQ_ * D_, HD_};
                gemm_bf(stream, CM_F32, Aq, Bk, sb, nullptr, nullptr,
                        SQ_, (long long)H_ * SQ_ * SQ_, (long long)SQ_ * SQ_,
                        SQ_, SQ_, HD_, B_ * H_, H_, iscale, nullptr, nullptr);
            }
            k_softmax<<<B_ * H_ * SQ_, 256, 0, stream>>>(sb, ph, pl, SQ_, 0);
            {
                BfMat Ap = {ph, pl, SQ_, (long long)H_ * SQ_ * SQ_, (long long)SQ_ * SQ_};
                BfMat Bv = {vth, vtl, B_ * SQ_, SQ_, (long long)HD_ * B_ * SQ_};
                gemm_bf(stream, CM_PAIR, Ap, Bv, nullptr, ctxh, ctxl,
                        D_, (long long)SQ_ * D_, HD_,
                        SQ_, HD_, SQ_, B_ * H_, H_, 1.f, nullptr, nullptr);
            }
            split_w(stream, wo + woff, wsh, wsl, 1048576);
            {
                BfMat Actx = {ctxh, ctxl, D_, 0, 0};
                gemm_bf(stream, CM_F32, Actx, Wscr, xb, nullptr, nullptr, D_, 0, 0,
                        B_ * SQ_, D_, D_, 1, 1, 1.f, nullptr, xb);
            }

            k_rmsnorm<<<B_ * SQ_, 256, 0, stream>>>(xb, n2w + l * D_, nullptr, hbh, hbl);
            split_w(stream, wg + foff, wsh, wsl, 4194304);
            gemm_bf(stream, CM_F32, Ahb, Wscr, ffg, nullptr, nullptr, FF_, 0, 0,
                    B_ * SQ_, FF_, D_, 1, 1, 1.f, nullptr, nullptr);
            split_w(stream, wu + foff, wsh, wsl, 4194304);
            gemm_bf(stream, CM_F32, Ahb, Wscr, ffu, nullptr, nullptr, FF_, 0, 0,
                    B_ * SQ_, FF_, D_, 1, 1, 1.f, nullptr, nullptr);
            k_silu_mul<<<32768, 256, 0, stream>>>(ffg, ffu, ffh, ffl);
            split_w(stream, wdn + foff, wsh, wsl, 4194304);
            {
                BfMat Aff = {ffh, ffl, FF_, 0, 0};
                BfMat Wd  = {wsh, wsl, FF_, 0, 0};
                gemm_bf(stream, CM_F32, Aff, Wd, xb, nullptr, nullptr, D_, 0, 0,
                        B_ * SQ_, D_, FF_, 1, 1, 1.f, nullptr, xb);
            }
        }

        // --- final ---
        k_rmsnorm<<<B_ * SQ_, 256, 0, stream>>>(xb, gnw, qb, hbh, hbl);
        {
            int chunks[4] = {8192, 8192, 8192, 7424};
            int coff = 0;
            for (int c = 0; c < 4; ++c) {
                split_w(stream, lmw + (size_t)coff * D_, wsh, wsl, (long long)chunks[c] * D_);
                gemm_bf(stream, CM_F32, Ahb, Wscr, logits + coff, nullptr, nullptr,
                        VOCAB_, 0, 0, B_ * SQ_, chunks[c], D_, 1, 1, 1.f, nullptr, nullptr);
                coff += chunks[c];
            }
        }
        k_meanpool_p1<<<32, 256, 0, stream>>>(qb, mpart);
        k_meanpool_p2<<<8, 256, 0, stream>>>(mpart, pooled);
        skinny(stream, pooled, D_, mw1, D_, mb1, mbuf, 256, B_, 256, D_, 1);
        skinny(stream, mbuf, 256, mw2, 256, mb2, meta, 3, B_, 3, 256, 0);
        return;
    }

    // =================== fp32 fallback path (round-1, verified) ===================
    float* ws    = (float*)d_ws;
    float* allkv = ws;
    float* xb    = allkv + 4194304;
    float* hb    = xb + 2097152;
    float* qb    = hb + 2097152;
    float* ctx   = qb + 2097152;
    float* ob    = ctx + 2097152;
    float* kb    = ob + 2097152;
    float* vb    = kb + 4194304;
    float* sb    = vb + 4194304;
    float* ffg   = sb;
    float* ffu   = sb + 8388608;
    float* sml2  = sb + 16777216;
    float* summ  = sml2;
    float* agh   = summ + 8192;
    float* ago   = agh + 4096;
    float* agr   = ago + 2048;
    float* pooled= agr + 2048;
    float* mbuf  = pooled + 2048;
    if (ws_size < (size_t)39911424 * 4) return;

    k_weighted_kv<<<4096, 256, 0, stream>>>(rh, conf, allkv, nullptr, nullptr);
    k_summaries<<<32, 256, 0, stream>>>(rh, summ);
    hipMemcpyAsync(xb, qh, (size_t)2097152 * 4, hipMemcpyDeviceToDevice, stream);

    for (int i = 0; i < 2; ++i) {
        const float* inw = cainw + (size_t)i * 3 * D_ * D_;
        const float* inb = cainb + (size_t)i * 3 * D_;
        k_rmsnorm<<<B_ * SQ_, 256, 0, stream>>>(xb, cnorm + i * D_, hb, nullptr, nullptr);
        gemm(stream, hb, D_, 0, inw, D_, 0, qb, D_, 0, 1, B_ * SQ_, D_, D_, 1.f, inb, false);
        gemm(stream, allkv, D_, 0, inw + 1048576, D_, 0, kb, D_, 0, 1, B_ * SKVT_, D_, D_, 1.f, inb + D_, false);
        gemm(stream, allkv, D_, 0, inw + 2097152, D_, 0, vb, D_, 0, 1, B_ * SKVT_, D_, D_, 1.f, inb + 2 * D_, false);
        for (int b = 0; b < B_; ++b) {
            gemm(stream, qb + (size_t)b * SQ_ * D_, D_, HD_,
                 kb + (size_t)b * SKVT_ * D_, D_, HD_,
                 sb, SKVT_, (long long)SQ_ * SKVT_,
                 H_, SQ_, SKVT_, HD_, iscale, nullptr, false);
            k_softmax<<<H_ * SQ_, 256, 0, stream>>>(sb, nullptr, nullptr, SKVT_, 1);
            if (i == 1)
                k_attn_mean<<<8192, 256, 0, stream>>>(sb, attnw + (size_t)b * SQ_ * SKVT_);
            gemm(stream, sb, SKVT_, (long long)SQ_ * SKVT_,
                 vb + (size_t)b * SKVT_ * D_, D_, HD_,
                 ctx + (size_t)b * SQ_ * D_, D_, HD_,
                 H_, SQ_, HD_, SKVT_, 1.f, nullptr, true);
        }
        gemm(stream, ctx, D_, 0, caoutw + (size_t)i * D_ * D_, D_, 0, ob, D_, 0,
             1, B_ * SQ_, D_, D_, 1.f, caoutb + i * D_, false);
        k_add<<<2048, 256, 0, stream>>>(xb, ob);
    }

    gemm(stream, summ, NR_ * D_, 0, agw1, NR_ * D_, 0, agh, 2 * D_, 0,
         1, B_, 2 * D_, NR_ * D_, 1.f, agb1, false);
    k_gelu<<<16, 256, 0, stream>>>(agh, B_ * 2 * D_);
    gemm(stream, agh, 2 * D_, 0, agw2, 2 * D_, 0, ago, D_, 0,
         1, B_, D_, 2 * D_, 1.f, agb2, false);
    k_rmsnorm<<<B_, 256, 0, stream>>>(ago, agnw, agr, nullptr, nullptr);
    k_add_bcast<<<8192, 256, 0, stream>>>(xb, agr);

    for (int l = 0; l < NL_; ++l) {
        const size_t woff = (size_t)l * D_ * D_;
        const size_t foff = (size_t)l * FF_ * D_;
        k_rmsnorm<<<B_ * SQ_, 256, 0, stream>>>(xb, n1w + l * D_, hb, nullptr, nullptr);
        gemm(stream, hb, D_, 0, wq + woff, D_, 0, qb, D_, 0, 1, B_ * SQ_, D_, D_, 1.f, nullptr, false);
        gemm(stream, hb, D_, 0, wk + woff, D_, 0, kb, D_, 0, 1, B_ * SQ_, D_, D_, 1.f, nullptr, false);
        gemm(stream, hb, D_, 0, wv + woff, D_, 0, vb, D_, 0, 1, B_ * SQ_, D_, D_, 1.f, nullptr, false);
        k_rope<<<4096, 256, 0, stream>>>(qb, kb, nullptr, nullptr, nullptr, nullptr);
        for (int b = 0; b < B_; ++b) {
            gemm(stream, qb + (size_t)b * SQ_ * D_, D_, HD_,
                 kb + (size_t)b * SQ_ * D_, D_, HD_,
                 sb, SQ_, (long long)SQ_ * SQ_,
                 H_, SQ_, SQ_, HD_, iscale, nullptr, false);
            k_softmax<<<H_ * SQ_, 256, 0, stream>>>(sb, nullptr, nullptr, SQ_, 1);
            gemm(stream, sb, SQ_, (long long)SQ_ * SQ_,
                 vb + (size_t)b * SQ_ * D_, D_, HD_,
                 ctx + (size_t)b * SQ_ * D_, D_, HD_,
                 H_, SQ_, HD_, SQ_, 1.f, nullptr, true);
        }
        gemm(stream, ctx, D_, 0, wo + woff, D_, 0, ob, D_, 0, 1, B_ * SQ_, D_, D_, 1.f, nullptr, false);
        k_add<<<2048, 256, 0, stream>>>(xb, ob);

        k_rmsnorm<<<B_ * SQ_, 256, 0, stream>>>(xb, n2w + l * D_, hb, nullptr, nullptr);
        gemm(stream, hb, D_, 0, wg + foff, D_, 0, ffg, FF_, 0, 1, B_ * SQ_, FF_, D_, 1.f, nullptr, false);
        gemm(stream, hb, D_, 0, wu + foff, D_, 0, ffu, FF_, 0, 1, B_ * SQ_, FF_, D_, 1.f, nullptr, false);
        k_silu_mul<<<32768, 256, 0, stream>>>(ffg, ffu, nullptr, nullptr);
        gemm(stream, ffg, FF_, 0, wdn + foff, FF_, 0, ob, D_, 0, 1, B_ * SQ_, D_, FF_, 1.f, nullptr, false);
        k_add<<<2048, 256, 0, stream>>>(xb, ob);
    }

    k_rmsnorm<<<B_ * SQ_, 256, 0, stream>>>(xb, gnw, hb, nullptr, nullptr);
    gemm(stream, hb, D_, 0, lmw, D_, 0, logits, VOCAB_, 0,
         1, B_ * SQ_, VOCAB_, D_, 1.f, nullptr, false);
    k_meanpool<<<8, 256, 0, stream>>>(hb, pooled);
    gemm(stream, pooled, D_, 0, mw1, D_, 0, mbuf, 256, 0,
         1, B_, 256, D_, 1.f, mb1, false);
    k_gelu<<<2, 256, 0, stream>>>(mbuf, B_ * 256);
    gemm(stream, mbuf, 256, 0, mw2, 256, 0, meta, 3, 0,
         1, B_, 3, 256, 1.f, mb2, false);
}